// Round 10
// baseline (795.413 us; speedup 1.0000x reference)
//
#include <hip/hip_runtime.h>

#define NN 50000
#define NE 800000
#define HD 128
#define NL 4
#define NC 10
#define NG 256
#define NBK 12500         // CSR buckets of 4 nodes (NN = 4*NBK exactly)

typedef __attribute__((ext_vector_type(8))) short short8;    // 8 bf16 = 4 VGPR (MFMA A/B frag)
typedef __attribute__((ext_vector_type(4))) float floatx4;   // MFMA C/D frag

union frg { uint4 u; short8 s; };

__device__ __forceinline__ short8 load_frag(const ushort* p){
  frg f; f.u = *(const uint4*)p; return f.s;
}
__device__ __forceinline__ floatx4 MFMA(short8 a, short8 b, floatx4 c){
  return __builtin_amdgcn_mfma_f32_16x16x32_bf16(a, b, c, 0, 0, 0);
}

__device__ __forceinline__ ushort f2bf(float x){           // RNE fp32->bf16
  unsigned u = __float_as_uint(x);
  return (ushort)((u + 0x7FFFu + ((u >> 16) & 1u)) >> 16);
}
__device__ __forceinline__ float bf2f(ushort b){
  return __uint_as_float(((uint)b) << 16);
}
__device__ __forceinline__ float sigmf(float x){ return 1.0f/(1.0f + __expf(-x)); }
__device__ __forceinline__ float tanhff(float x){ return 2.0f/(1.0f + __expf(-2.0f*x)) - 1.0f; }

// ---------------- prep: convert whh / local_w to bf16; fold biases ----------------
__global__ __launch_bounds__(256) void prep_weights_bf16(
    const float* __restrict__ w_hh, const float* __restrict__ local_w,
    const float* __restrict__ b_ih, const float* __restrict__ b_hh,
    ushort* __restrict__ whh_bf, ushort* __restrict__ lw_bf,
    float* __restrict__ bs)
{
  int idx = blockIdx.x*256 + threadIdx.x;
  if (idx < 49152) whh_bf[idx] = f2bf(w_hh[idx]);
  else if (idx < 65536){ int j = idx - 49152; lw_bf[j] = f2bf(local_w[j]); }
  else if (idx < 66048){
    int j = idx - 65536;       // 0..511: br(128), bz(128), bin(128), bhn(128)
    if (j < 256)      bs[j] = b_ih[j] + b_hh[j];
    else if (j < 384) bs[j] = b_ih[j];          // bin
    else              bs[j] = b_hh[j - 128];    // bhn
  }
}

// ---------------- Veff[l]^T[o][j] = sum_f W[l][j][f] * wih[o][f]  (fp32 acc -> bf16) ----------------
__global__ __launch_bounds__(256) void veff_kernel(
    const float* __restrict__ W, const float* __restrict__ w_ih,
    ushort* __restrict__ veffT)
{
  int idx = blockIdx.x*256 + threadIdx.x;    // l*49152 + o*128 + j
  if (idx >= 4*49152) return;
  int l = idx / 49152, rem = idx % 49152;
  int o = rem >> 7, j = rem & 127;
  const float4* wr = (const float4*)&W[(size_t)(l*128 + j)*128];
  const float4* ir = (const float4*)&w_ih[(size_t)o*128];
  float acc = 0.f;
  #pragma unroll
  for (int q = 0; q < 32; q++){
    float4 a = wr[q], b = ir[q];
    acc += a.x*b.x + a.y*b.y + a.z*b.z + a.w*b.w;
  }
  veffT[idx] = f2bf(acc);
}

__global__ __launch_bounds__(256) void convert_x(const float4* __restrict__ x, ushort4* __restrict__ xbf)
{
  int i = blockIdx.x*256 + threadIdx.x;
  if (i < NN*HD/4){
    float4 v = x[i];
    ushort4 o; o.x=f2bf(v.x); o.y=f2bf(v.y); o.z=f2bf(v.z); o.w=f2bf(v.w);
    xbf[i] = o;
  }
}

// ---------------- CSR build ----------------
__global__ __launch_bounds__(256) void count_deg(const int* __restrict__ dst, int* deg)
{
  int e = blockIdx.x*256 + threadIdx.x;
  if (e < NE){
    int d = __builtin_nontemporal_load(&dst[e]);
    atomicAdd(&deg[d], 1);
  }
}

__global__ __launch_bounds__(1024) void scan_blocks(
    const int* __restrict__ deg, int* __restrict__ excl_out, int* __restrict__ bsum)
{
  __shared__ int wsum[16];
  int t = threadIdx.x;
  int gid = blockIdx.x*1024 + t;
  int v = (gid < NN) ? deg[gid] : 0;
  int lane = t & 63, wv = t >> 6;
  int incl = v;
  #pragma unroll
  for (int off=1; off<64; off<<=1){
    int y = __shfl_up(incl, off, 64);
    if (lane >= off) incl += y;
  }
  if (lane == 63) wsum[wv] = incl;
  __syncthreads();
  if (wv == 0){
    int s = (lane < 16) ? wsum[lane] : 0;
    #pragma unroll
    for (int off=1; off<16; off<<=1){
      int y = __shfl_up(s, off, 64);
      if (lane >= off) s += y;
    }
    if (lane < 16) wsum[lane] = s;
  }
  __syncthreads();
  int wpre = (wv > 0) ? wsum[wv-1] : 0;
  if (gid < NN) excl_out[gid] = wpre + incl - v;
  if (t == 1023) bsum[blockIdx.x] = wpre + incl;
}

__global__ __launch_bounds__(64) void scan_carry(int* bsum, int* __restrict__ row_ptr)
{
  int lane = threadIdx.x;
  int v = (lane < 49) ? bsum[lane] : 0;
  int incl = v;
  #pragma unroll
  for (int off=1; off<64; off<<=1){
    int y = __shfl_up(incl, off, 64);
    if (lane >= off) incl += y;
  }
  if (lane < 49) bsum[lane] = incl - v;
  if (lane == 0) row_ptr[NN] = NE;
}

__global__ __launch_bounds__(1024) void scan_add(
    const int* __restrict__ bsum, int* __restrict__ row_ptr)
{
  int gid = blockIdx.x*1024 + threadIdx.x;
  if (gid < NN) row_ptr[gid] += bsum[blockIdx.x];
}

// bcur[b] = row_ptr[b*4]  (bucket write cursors for pair scatter)
__global__ __launch_bounds__(256) void bucket_init(const int* __restrict__ row_ptr, int* __restrict__ bcur)
{
  int b = blockIdx.x*256 + threadIdx.x;
  if (b < NBK) bcur[b] = row_ptr[b*4];
}

// Pass A: scatter packed (src | local_dst<<17) into 4-node bucket regions.
// 12500 tails keep atomic chains ~64 deep (round-8 lesson) and writes line-dense.
__global__ __launch_bounds__(256) void fill_pairs(
    const int* __restrict__ src, const int* __restrict__ dst,
    int* bcur, uint* __restrict__ pairs)
{
  int e = blockIdx.x*256 + threadIdx.x;
  if (e < NE){
    int s = __builtin_nontemporal_load(&src[e]);
    int d = __builtin_nontemporal_load(&dst[e]);
    int b = d >> 2;
    int pos = atomicAdd(&bcur[b], 1);
    pairs[pos] = (uint)s | ((uint)(d & 3) << 17);
  }
}

// Pass B: one wave per bucket; 4 per-node cursors in LDS.
__global__ __launch_bounds__(64) void fill_csr_bucket(
    const uint* __restrict__ pairs, const int* __restrict__ row_ptr,
    int* __restrict__ csr_src)
{
  __shared__ int lcur[4];
  int b = blockIdx.x;
  int n0 = b*4;
  int base = row_ptr[n0];
  int end  = row_ptr[n0+4];
  int t = threadIdx.x;
  if (t < 4) lcur[t] = row_ptr[n0 + t] - base;
  __syncthreads();
  for (int p = base + t; p < end; p += 64){
    uint pk = pairs[p];
    int ld = pk >> 17;
    int pos = atomicAdd(&lcur[ld], 1);
    csr_src[base + pos] = (int)(pk & 0x1FFFFu);
  }
}

__global__ __launch_bounds__(64) void graph_ptr_kernel(const int* __restrict__ batch, int* __restrict__ gptr)
{
  int g = blockIdx.x*64 + threadIdx.x;
  if (g > NG) return;
  int lo = 0, hi = NN;
  while (lo < hi){
    int mid = (lo + hi) >> 1;
    if (batch[mid] < g) lo = mid + 1; else hi = mid;
  }
  gptr[g] = lo;
}

// ---------------- K3: fused aggregate + GRU via MFMA; 64 nodes/block ----------------
// Ping-pong h buffers (gather reads arbitrary rows of hin; writes only own rows of hout).
// LDS input tiles use XOR-swizzled blocks: addr(n,k) = n*128 + ((k>>3)^(n&15))*8 + (k&7)
//   -> gather b32 writes 2-way (free), frag b128 reads standard phase pattern.
__global__ __launch_bounds__(256, 2) void gru_fused_agg(
    const ushort* __restrict__ hin, ushort* __restrict__ hout,
    const int* __restrict__ row_ptr, const int* __restrict__ csr_src,
    const ushort* __restrict__ veffT, const ushort* __restrict__ whh_bf,
    const float* __restrict__ bs)
{
  __shared__ __align__(16) ushort S[8192];             // 16 KB sumh tile (swizzled)
  __shared__ __align__(16) ushort Hh[8192];            // 16 KB h tile (swizzled)
  __shared__ __align__(16) ushort lds_out[64*136];     // 17 KB hv bf16, stride 136
  int t = threadIdx.x;
  int wv = t >> 6, lane = t & 63;
  int mrow = lane & 15, quad = lane >> 4;
  int nb = blockIdx.x * 64;
  const uint* hin_u = (const uint*)hin;

  // stage own h rows (vector, 16B): 4 iters x 256 threads = 64 nodes x 16 k-blocks
  #pragma unroll
  for (int it = 0; it < 4; it++){
    int idx = it*256 + t;
    int nl = idx >> 4, kb = idx & 15;
    int ng = nb + nl; if (ng >= NN) ng = NN-1;
    uint4 v = *(const uint4*)&hin[(size_t)ng*HD + kb*8];
    *(uint4*)((char*)Hh + nl*256 + ((kb ^ (nl & 15))*16)) = v;
  }

  // gather sumh for own nodes: wave wv handles 16 nodes; lane = uint column (2 feats)
  for (int nl8 = 0; nl8 < 16; nl8++){
    int nl = wv*16 + nl8;
    int nd = nb + nl;
    float ax = 0.f, ay = 0.f;
    if (nd < NN){
      int s0 = row_ptr[nd], s1 = row_ptr[nd+1];
      int j = s0;
      for (; j + 7 < s1; j += 8){
        int si[8]; uint vvv[8];
        #pragma unroll
        for (int q=0;q<8;q++) si[q] = csr_src[j+q];
        #pragma unroll
        for (int q=0;q<8;q++) vvv[q] = hin_u[(size_t)si[q]*64 + lane];
        #pragma unroll
        for (int q=0;q<8;q++){
          ax += __uint_as_float(vvv[q] << 16);
          ay += __uint_as_float(vvv[q] & 0xFFFF0000u);
        }
      }
      for (; j < s1; j++){
        int s = csr_src[j];
        uint v = hin_u[(size_t)s*64 + lane];
        ax += __uint_as_float(v << 16);
        ay += __uint_as_float(v & 0xFFFF0000u);
      }
    }
    uint pk = (uint)f2bf(ax) | ((uint)f2bf(ay) << 16);
    // k = 2*lane: block = (lane>>2)^(nl&15), within-block byte = (lane&3)*4
    *(uint*)((char*)S + nl*256 + (((lane>>2) ^ (nl & 15))*16) + (lane & 3)*4) = pk;
  }
  __syncthreads();

  floatx4 aR[4][2] = {}, aZ[4][2] = {}, aIN[4][2] = {}, aHN[4][2] = {};

  #pragma unroll
  for (int kc = 0; kc < 4; kc++){
    int k0 = kc*32 + quad*8;
    short8 fa[4], fh[4];
    #pragma unroll
    for (int tt = 0; tt < 4; tt++){
      int off = (tt*16 + mrow)*256 + (((kc*4 + quad) ^ mrow)*16);
      fa[tt] = load_frag((const ushort*)((const char*)S  + off));
      fh[tt] = load_frag((const ushort*)((const char*)Hh + off));
    }
    #pragma unroll
    for (int ftl = 0; ftl < 2; ftl++){
      size_t wo = (size_t)((wv*2 + ftl)*16 + mrow)*HD + k0;
      short8 vir = load_frag(&veffT[wo]);
      short8 viz = load_frag(&veffT[128*HD + wo]);
      short8 vin = load_frag(&veffT[256*HD + wo]);
      short8 whr = load_frag(&whh_bf[wo]);
      short8 whz = load_frag(&whh_bf[128*HD + wo]);
      short8 whn = load_frag(&whh_bf[256*HD + wo]);
      #pragma unroll
      for (int tt = 0; tt < 4; tt++){
        aR[tt][ftl]  = MFMA(fa[tt], vir, aR[tt][ftl]);
        aR[tt][ftl]  = MFMA(fh[tt], whr, aR[tt][ftl]);
        aZ[tt][ftl]  = MFMA(fa[tt], viz, aZ[tt][ftl]);
        aZ[tt][ftl]  = MFMA(fh[tt], whz, aZ[tt][ftl]);
        aIN[tt][ftl] = MFMA(fa[tt], vin, aIN[tt][ftl]);
        aHN[tt][ftl] = MFMA(fh[tt], whn, aHN[tt][ftl]);
      }
    }
  }

  // epilogue: gates fp32; ho from swizzled Hh tile; hv -> lds_out bf16
  #pragma unroll
  for (int ftl = 0; ftl < 2; ftl++){
    int feat = wv*32 + ftl*16 + mrow;
    float br  = bs[feat], bz = bs[128+feat], bin = bs[256+feat], bhn = bs[384+feat];
    int fb = feat >> 3, fj = feat & 7;          // swizzle block / within-block of feat
    #pragma unroll
    for (int tt = 0; tt < 4; tt++){
      #pragma unroll
      for (int r = 0; r < 4; r++){
        int nrow = quad*4 + r;
        int n = tt*16 + nrow;
        float rr = sigmf(aR[tt][ftl][r] + br);
        float zz = sigmf(aZ[tt][ftl][r] + bz);
        float nn = tanhff(aIN[tt][ftl][r] + bin + rr*(aHN[tt][ftl][r] + bhn));
        float ho = bf2f(*(const ushort*)((const char*)Hh + n*256 + (((fb ^ nrow)*8 + fj)*2)));
        float hv = (1.f - zz)*nn + zz*ho;
        lds_out[n*136 + feat] = f2bf(hv);
      }
    }
  }
  __syncthreads();

  // coalesced write-back: 1024 chunks of 8 ushorts (16 B)
  #pragma unroll
  for (int p = 0; p < 4; p++){
    int chunk = p*256 + t;
    int node = chunk >> 4, f = (chunk & 15)*8;
    int ng = nb + node;
    if (ng < NN){
      uint4 v = *(const uint4*)&lds_out[node*136 + f];
      *(uint4*)&hout[(size_t)ng*HD + f] = v;
    }
  }
}

// ---------------- local head: relu(hbf @ local_w^T + b) -> fp32 ----------------
__global__ __launch_bounds__(256) void local_gemm_mfma(
    const ushort* __restrict__ hbf, const ushort* __restrict__ lw_bf,
    const float* __restrict__ bias, float* __restrict__ local)
{
  int wv = threadIdx.x >> 6, lane = threadIdx.x & 63;
  int mt = blockIdx.x*4 + wv;
  if (mt >= NN/16) return;
  int m0 = mt*16, mrow = lane & 15, quad = lane >> 4;
  floatx4 acc[8] = {};
  for (int kc = 0; kc < 4; kc++){
    int k0 = kc*32 + quad*8;
    short8 a = load_frag(&hbf[(size_t)(m0 + mrow)*HD + k0]);
    #pragma unroll
    for (int ft = 0; ft < 8; ft++){
      short8 b = load_frag(&lw_bf[(size_t)(ft*16 + mrow)*HD + k0]);
      acc[ft] = MFMA(a, b, acc[ft]);
    }
  }
  #pragma unroll
  for (int ft = 0; ft < 8; ft++){
    float bv = bias[ft*16 + mrow];
    #pragma unroll
    for (int r = 0; r < 4; r++){
      int n = m0 + quad*4 + r;
      local[(size_t)n*HD + ft*16 + mrow] = fmaxf(acc[ft][r] + bv, 0.f);
    }
  }
}

// ---------------- segmented mean-pool (batch sorted, zero atomics) ----------------
__global__ __launch_bounds__(256) void pool_kernel(
    const float* __restrict__ local, const int* __restrict__ gptr,
    float* __restrict__ pooled)
{
  __shared__ float4 red[8][32];
  int g = blockIdx.x;
  int lane = threadIdx.x & 31;
  int st = threadIdx.x >> 5;
  int s0 = gptr[g], s1 = gptr[g+1];
  float4 acc = make_float4(0,0,0,0);
  for (int n = s0 + st; n < s1; n += 8){
    float4 v = *(const float4*)&local[(size_t)n*HD + lane*4];
    acc.x += v.x; acc.y += v.y; acc.z += v.z; acc.w += v.w;
  }
  red[st][lane] = acc;
  __syncthreads();
  if (st == 0){
    float4 s = red[0][lane];
    #pragma unroll
    for (int i=1;i<8;i++){
      float4 v = red[i][lane];
      s.x += v.x; s.y += v.y; s.z += v.z; s.w += v.w;
    }
    float cnt = (float)(s1 - s0);
    if (cnt < 1.0f) cnt = 1.0f;
    float inv = 1.0f / cnt;
    s.x *= inv; s.y *= inv; s.z *= inv; s.w *= inv;
    *(float4*)&pooled[g*HD + lane*4] = s;
  }
}

// ---------------- classifier + log_softmax ----------------
__global__ __launch_bounds__(64) void classifier_kernel(
    const float* __restrict__ pooled,
    const float* __restrict__ gw, const float* __restrict__ gb,
    float* __restrict__ out)
{
  int g = blockIdx.x;
  int lane = threadIdx.x;
  float p0 = pooled[g*HD + lane];
  float p1 = pooled[g*HD + 64 + lane];
  float vals[NC];
  #pragma unroll
  for (int c=0;c<NC;c++){
    float s = p0*gw[c*HD + lane] + p1*gw[c*HD + 64 + lane];
    #pragma unroll
    for (int off=32; off>0; off>>=1) s += __shfl_down(s, off, 64);
    vals[c] = s;
  }
  if (lane == 0){
    float mx = -1e30f;
    #pragma unroll
    for (int c=0;c<NC;c++){ vals[c] += gb[c]; mx = fmaxf(mx, vals[c]); }
    float se = 0.f;
    #pragma unroll
    for (int c=0;c<NC;c++) se += __expf(vals[c] - mx);
    float lse = mx + __logf(se);
    #pragma unroll
    for (int c=0;c<NC;c++) out[g*NC + c] = vals[c] - lse;
  }
}

extern "C" void kernel_launch(void* const* d_in, const int* in_sizes, int n_in,
                              void* d_out, int out_size, void* d_ws, size_t ws_size,
                              hipStream_t stream)
{
  const float* x        = (const float*)d_in[0];
  const int*   ei       = (const int*)  d_in[1];
  const int*   batch    = (const int*)  d_in[2];
  const float* W        = (const float*)d_in[3];
  const float* w_ih     = (const float*)d_in[4];
  const float* w_hh     = (const float*)d_in[5];
  const float* b_ih     = (const float*)d_in[6];
  const float* b_hh     = (const float*)d_in[7];
  const float* local_w  = (const float*)d_in[8];
  const float* local_b  = (const float*)d_in[9];
  const float* global_w = (const float*)d_in[10];
  const float* global_b = (const float*)d_in[11];
  float* out = (float*)d_out;

  // workspace layout
  char* base = (char*)d_ws;
  ushort* hB      = (ushort*)base;                    // 12.8 MB ping-pong h (B); pairs alias pre-layers
  uint*   pairs   = (uint*)base;                      //   3.2 MB (CSR build only, before layers)
  int*    bcur    = (int*)(base + 3200000);           //   50 KB  (CSR build only)
  char*   R       = base + 25600000;                  // 25.6 MB multi-use region
  ushort* veffT   = (ushort*)(R + 12800000);          //   384 KB (live during layers)
  ushort* whh_bf  = (ushort*)(R + 13193216);          //   96 KB  (live during layers)
  float*  bsums   = (float*)(R + 13291520);           //   2 KB   (live during layers)
  float*  local   = (float*)R;                        //   25.6 MB (after layers; clobbers veff/whh)
  ushort* xbf     = (ushort*)(base + 51200000);       // 12.8 MB
  ushort* hA      = (ushort*)(base + 64000000);       // 12.8 MB ping-pong h (A)
  ushort* lw_bf   = (ushort*)(base + 76800000);       // 32 KB
  float*  pooled  = (float*)(base + 76832768);        // 128 KB
  int* row_ptr    = (int*)(base + 76963840);          // NN+1
  int* deg        = row_ptr + (NN + 1);               // NN
  int* csr_src    = deg + NN;                         // NE
  int* gptr       = csr_src + NE;                     // NG+1
  int* bsum       = gptr + (NG + 1);                  // 49

  const int* esrc = ei;
  const int* edst = ei + NE;

  hipMemsetAsync(deg, 0, NN*sizeof(int), stream);
  prep_weights_bf16<<<259, 256, 0, stream>>>(w_hh, local_w, b_ih, b_hh, whh_bf, lw_bf, bsums);
  veff_kernel<<<768, 256, 0, stream>>>(W, w_ih, veffT);
  convert_x<<<6250, 256, 0, stream>>>((const float4*)x, (ushort4*)xbf);
  count_deg<<<3125, 256, 0, stream>>>(edst, deg);
  scan_blocks<<<49, 1024, 0, stream>>>(deg, row_ptr, bsum);
  scan_carry<<<1, 64, 0, stream>>>(bsum, row_ptr);
  scan_add<<<49, 1024, 0, stream>>>(bsum, row_ptr);
  bucket_init<<<49, 256, 0, stream>>>(row_ptr, bcur);
  fill_pairs<<<3125, 256, 0, stream>>>(esrc, edst, bcur, pairs);
  fill_csr_bucket<<<NBK, 64, 0, stream>>>(pairs, row_ptr, csr_src);
  graph_ptr_kernel<<<5, 64, 0, stream>>>(batch, gptr);

  // fused layers, ping-pong: x->A, A->B, B->A, A->B  (final h in hB)
  gru_fused_agg<<<782, 256, 0, stream>>>(xbf, hA, row_ptr, csr_src, veffT,             whh_bf, bsums);
  gru_fused_agg<<<782, 256, 0, stream>>>(hA,  hB, row_ptr, csr_src, veffT + 49152,     whh_bf, bsums);
  gru_fused_agg<<<782, 256, 0, stream>>>(hB,  hA, row_ptr, csr_src, veffT + 2*49152,   whh_bf, bsums);
  gru_fused_agg<<<782, 256, 0, stream>>>(hA,  hB, row_ptr, csr_src, veffT + 3*49152,   whh_bf, bsums);

  local_gemm_mfma<<<782, 256, 0, stream>>>(hB, lw_bf, local_b, local);
  pool_kernel<<<NG, 256, 0, stream>>>(local, gptr, pooled);
  classifier_kernel<<<NG, 64, 0, stream>>>(pooled, global_w, global_b, out);
}

// Round 11
// 729.252 us; speedup vs baseline: 1.0907x; 1.0907x over previous
//
#include <hip/hip_runtime.h>

#define NN 50000
#define NE 800000
#define HD 128
#define NL 4
#define NC 10
#define NG 256
#define NBK 12500         // CSR buckets of 4 nodes (NN = 4*NBK exactly)

typedef __attribute__((ext_vector_type(8))) short short8;    // 8 bf16 = 4 VGPR (MFMA A/B frag)
typedef __attribute__((ext_vector_type(4))) float floatx4;   // MFMA C/D frag

union frg { uint4 u; short8 s; };

__device__ __forceinline__ short8 load_frag(const ushort* p){
  frg f; f.u = *(const uint4*)p; return f.s;
}
__device__ __forceinline__ floatx4 MFMA(short8 a, short8 b, floatx4 c){
  return __builtin_amdgcn_mfma_f32_16x16x32_bf16(a, b, c, 0, 0, 0);
}

__device__ __forceinline__ ushort f2bf(float x){           // RNE fp32->bf16
  unsigned u = __float_as_uint(x);
  return (ushort)((u + 0x7FFFu + ((u >> 16) & 1u)) >> 16);
}
__device__ __forceinline__ float bf2f(ushort b){
  return __uint_as_float(((uint)b) << 16);
}
__device__ __forceinline__ float sigmf(float x){ return 1.0f/(1.0f + __expf(-x)); }
__device__ __forceinline__ float tanhff(float x){ return 2.0f/(1.0f + __expf(-2.0f*x)) - 1.0f; }

// ---------------- prep: convert whh / local_w to bf16; fold biases ----------------
__global__ __launch_bounds__(256) void prep_weights_bf16(
    const float* __restrict__ w_hh, const float* __restrict__ local_w,
    const float* __restrict__ b_ih, const float* __restrict__ b_hh,
    ushort* __restrict__ whh_bf, ushort* __restrict__ lw_bf,
    float* __restrict__ bs)
{
  int idx = blockIdx.x*256 + threadIdx.x;
  if (idx < 49152) whh_bf[idx] = f2bf(w_hh[idx]);
  else if (idx < 65536){ int j = idx - 49152; lw_bf[j] = f2bf(local_w[j]); }
  else if (idx < 66048){
    int j = idx - 65536;       // 0..511: br(128), bz(128), bin(128), bhn(128)
    if (j < 256)      bs[j] = b_ih[j] + b_hh[j];
    else if (j < 384) bs[j] = b_ih[j];          // bin
    else              bs[j] = b_hh[j - 128];    // bhn
  }
}

// ---------------- Veff[l]^T[o][j] = sum_f W[l][j][f] * wih[o][f]  (fp32 acc -> bf16) ----------------
__global__ __launch_bounds__(256) void veff_kernel(
    const float* __restrict__ W, const float* __restrict__ w_ih,
    ushort* __restrict__ veffT)
{
  int idx = blockIdx.x*256 + threadIdx.x;    // l*49152 + o*128 + j
  if (idx >= 4*49152) return;
  int l = idx / 49152, rem = idx % 49152;
  int o = rem >> 7, j = rem & 127;
  const float4* wr = (const float4*)&W[(size_t)(l*128 + j)*128];
  const float4* ir = (const float4*)&w_ih[(size_t)o*128];
  float acc = 0.f;
  #pragma unroll
  for (int q = 0; q < 32; q++){
    float4 a = wr[q], b = ir[q];
    acc += a.x*b.x + a.y*b.y + a.z*b.z + a.w*b.w;
  }
  veffT[idx] = f2bf(acc);
}

__global__ __launch_bounds__(256) void convert_x(const float4* __restrict__ x, ushort4* __restrict__ xbf)
{
  int i = blockIdx.x*256 + threadIdx.x;
  if (i < NN*HD/4){
    float4 v = x[i];
    ushort4 o; o.x=f2bf(v.x); o.y=f2bf(v.y); o.z=f2bf(v.z); o.w=f2bf(v.w);
    xbf[i] = o;
  }
}

// ---------------- CSR build ----------------
__global__ __launch_bounds__(256) void count_deg(const int* __restrict__ dst, int* deg)
{
  int e = blockIdx.x*256 + threadIdx.x;
  if (e < NE){
    int d = __builtin_nontemporal_load(&dst[e]);
    atomicAdd(&deg[d], 1);
  }
}

__global__ __launch_bounds__(1024) void scan_blocks(
    const int* __restrict__ deg, int* __restrict__ excl_out, int* __restrict__ bsum)
{
  __shared__ int wsum[16];
  int t = threadIdx.x;
  int gid = blockIdx.x*1024 + t;
  int v = (gid < NN) ? deg[gid] : 0;
  int lane = t & 63, wv = t >> 6;
  int incl = v;
  #pragma unroll
  for (int off=1; off<64; off<<=1){
    int y = __shfl_up(incl, off, 64);
    if (lane >= off) incl += y;
  }
  if (lane == 63) wsum[wv] = incl;
  __syncthreads();
  if (wv == 0){
    int s = (lane < 16) ? wsum[lane] : 0;
    #pragma unroll
    for (int off=1; off<16; off<<=1){
      int y = __shfl_up(s, off, 64);
      if (lane >= off) s += y;
    }
    if (lane < 16) wsum[lane] = s;
  }
  __syncthreads();
  int wpre = (wv > 0) ? wsum[wv-1] : 0;
  if (gid < NN) excl_out[gid] = wpre + incl - v;
  if (t == 1023) bsum[blockIdx.x] = wpre + incl;
}

__global__ __launch_bounds__(64) void scan_carry(int* bsum, int* __restrict__ row_ptr)
{
  int lane = threadIdx.x;
  int v = (lane < 49) ? bsum[lane] : 0;
  int incl = v;
  #pragma unroll
  for (int off=1; off<64; off<<=1){
    int y = __shfl_up(incl, off, 64);
    if (lane >= off) incl += y;
  }
  if (lane < 49) bsum[lane] = incl - v;
  if (lane == 0) row_ptr[NN] = NE;
}

__global__ __launch_bounds__(1024) void scan_add(
    const int* __restrict__ bsum, int* __restrict__ row_ptr)
{
  int gid = blockIdx.x*1024 + threadIdx.x;
  if (gid < NN) row_ptr[gid] += bsum[blockIdx.x];
}

// bcur[b] = row_ptr[b*4]  (bucket write cursors for pair scatter)
__global__ __launch_bounds__(256) void bucket_init(const int* __restrict__ row_ptr, int* __restrict__ bcur)
{
  int b = blockIdx.x*256 + threadIdx.x;
  if (b < NBK) bcur[b] = row_ptr[b*4];
}

// Pass A: scatter packed (src | local_dst<<17) into 4-node bucket regions.
// 12500 tails keep atomic chains ~64 deep (round-8 lesson) and writes line-dense.
__global__ __launch_bounds__(256) void fill_pairs(
    const int* __restrict__ src, const int* __restrict__ dst,
    int* bcur, uint* __restrict__ pairs)
{
  int e = blockIdx.x*256 + threadIdx.x;
  if (e < NE){
    int s = __builtin_nontemporal_load(&src[e]);
    int d = __builtin_nontemporal_load(&dst[e]);
    int b = d >> 2;
    int pos = atomicAdd(&bcur[b], 1);
    pairs[pos] = (uint)s | ((uint)(d & 3) << 17);
  }
}

// Pass B: one wave per bucket; 4 per-node cursors in LDS.
__global__ __launch_bounds__(64) void fill_csr_bucket(
    const uint* __restrict__ pairs, const int* __restrict__ row_ptr,
    int* __restrict__ csr_src)
{
  __shared__ int lcur[4];
  int b = blockIdx.x;
  int n0 = b*4;
  int base = row_ptr[n0];
  int end  = row_ptr[n0+4];
  int t = threadIdx.x;
  if (t < 4) lcur[t] = row_ptr[n0 + t] - base;
  __syncthreads();
  for (int p = base + t; p < end; p += 64){
    uint pk = pairs[p];
    int ld = pk >> 17;
    int pos = atomicAdd(&lcur[ld], 1);
    csr_src[base + pos] = (int)(pk & 0x1FFFFu);
  }
}

__global__ __launch_bounds__(64) void graph_ptr_kernel(const int* __restrict__ batch, int* __restrict__ gptr)
{
  int g = blockIdx.x*64 + threadIdx.x;
  if (g > NG) return;
  int lo = 0, hi = NN;
  while (lo < hi){
    int mid = (lo + hi) >> 1;
    if (batch[mid] < g) lo = mid + 1; else hi = mid;
  }
  gptr[g] = lo;
}

// ---------------- K2: sumh[n] = sum_{e: dst=n} h[src]  (bf16 in, bf16 out) ----------------
// Separate high-occupancy kernel (round-10 lesson: gather needs ~32 waves/CU;
// never co-locate with the low-occupancy MFMA kernel).
__global__ __launch_bounds__(256) void aggregate_bf16(
    const uint* __restrict__ m, const int* __restrict__ row_ptr,
    const int* __restrict__ csr_src, uint* __restrict__ aggr)
{
  int nid = blockIdx.x*4 + (threadIdx.x >> 6);
  int lane = threadIdx.x & 63;
  if (nid >= NN) return;
  int s0 = row_ptr[nid], s1 = row_ptr[nid+1];
  float ax = 0.f, ay = 0.f;
  int j = s0;
  for (; j + 7 < s1; j += 8){
    int si[8]; uint vv[8];
    #pragma unroll
    for (int q=0;q<8;q++) si[q] = csr_src[j+q];
    #pragma unroll
    for (int q=0;q<8;q++) vv[q] = m[(size_t)si[q]*64 + lane];
    #pragma unroll
    for (int q=0;q<8;q++){
      ax += __uint_as_float(vv[q] << 16);
      ay += __uint_as_float(vv[q] & 0xFFFF0000u);
    }
  }
  for (; j < s1; j++){
    int s = csr_src[j];
    uint v = m[(size_t)s*64 + lane];
    ax += __uint_as_float(v << 16);
    ay += __uint_as_float(v & 0xFFFF0000u);
  }
  aggr[(size_t)nid*64 + lane] = (uint)f2bf(ax) | ((uint)f2bf(ay) << 16);
}

// ---------------- K3: GRU via MFMA; feat-split blocks for occupancy ----------------
// grid = 782 node-tiles x 4 feat-groups. Block = 64 nodes x 32 feats; wave wv owns
// one 16-node tile across the block's 32 feats. Accumulators 32 AGPR/thread (vs 128
// in the 128-feat variant) and 37 KB LDS -> ~4 waves/SIMD to hide weight-load latency.
// All 4 waves load IDENTICAL weight frags (same feats) -> L1/L2 broadcast reuse.
// Ping-pong h buffers required: feat-slice writers race with full-row readers in-place.
__global__ __launch_bounds__(256) void gru_mfma5(
    const ushort* __restrict__ sumh_bf, ushort* __restrict__ hout,
    const ushort* __restrict__ hin,
    const ushort* __restrict__ veffT, const ushort* __restrict__ whh_bf,
    const float* __restrict__ bs)
{
  __shared__ __align__(16) ushort lds_in[16384];       // 32 KB: 32 chunks of 1 KB
  __shared__ __align__(16) ushort lds_out[64*40];      // 5 KB hv bf16, stride 40
  int t = threadIdx.x;
  int wv = t >> 6, lane = t & 63;
  int mrow = lane & 15, quad = lane >> 4;
  int bi = blockIdx.x;
  int nt = bi >> 2, fg = bi & 3;
  int nb = nt * 64;

  // stage inputs: 32 chunks (arr{sumh,h}x16 + tt{0..3}x4 + kc{0..3})
  #pragma unroll
  for (int q = 0; q < 8; q++){
    int c = wv*8 + q;                      // c = arr*16 + tt*4 + kc
    int arr = c >> 4, tt = (c >> 2) & 3, kc = c & 3;
    const ushort* srcb = arr ? hin : sumh_bf;
    int node = nb + tt*16 + mrow; if (node >= NN) node = NN-1;
    uint4 v = *(const uint4*)&srcb[(size_t)node*HD + kc*32 + quad*8];
    *(uint4*)&lds_in[c*512 + lane*8] = v;
  }
  __syncthreads();

  floatx4 aR[2] = {}, aZ[2] = {}, aIN[2] = {}, aHN[2] = {};

  #pragma unroll
  for (int kc = 0; kc < 4; kc++){
    int k0 = kc*32 + quad*8;
    short8 fa = load_frag(&lds_in[((wv<<2) | kc)*512 + lane*8]);
    short8 fh = load_frag(&lds_in[(16 | (wv<<2) | kc)*512 + lane*8]);
    #pragma unroll
    for (int ftl = 0; ftl < 2; ftl++){
      size_t wo = (size_t)((fg*2 + ftl)*16 + mrow)*HD + k0;
      short8 vir = load_frag(&veffT[wo]);
      short8 viz = load_frag(&veffT[128*HD + wo]);
      short8 vin = load_frag(&veffT[256*HD + wo]);
      short8 whr = load_frag(&whh_bf[wo]);
      short8 whz = load_frag(&whh_bf[128*HD + wo]);
      short8 whn = load_frag(&whh_bf[256*HD + wo]);
      aR[ftl]  = MFMA(fa, vir, aR[ftl]);
      aR[ftl]  = MFMA(fh, whr, aR[ftl]);
      aZ[ftl]  = MFMA(fa, viz, aZ[ftl]);
      aZ[ftl]  = MFMA(fh, whz, aZ[ftl]);
      aIN[ftl] = MFMA(fa, vin, aIN[ftl]);
      aHN[ftl] = MFMA(fh, whn, aHN[ftl]);
    }
  }

  // epilogue: gates fp32; ho from staged h chunk (kc = fg); hv -> lds_out bf16
  #pragma unroll
  for (int ftl = 0; ftl < 2; ftl++){
    int feat = fg*32 + ftl*16 + mrow;
    float br  = bs[feat], bz = bs[128+feat], bin = bs[256+feat], bhn = bs[384+feat];
    int kw = ftl*16 + mrow;                      // k-position within fg's 32-feat span
    int qq = kw >> 3, jj = kw & 7;
    int cho = (16 | (wv<<2) | fg)*512;           // h chunk for this wave's tile, kc = fg
    #pragma unroll
    for (int r = 0; r < 4; r++){
      int nrow = quad*4 + r;
      float rr = sigmf(aR[ftl][r] + br);
      float zz = sigmf(aZ[ftl][r] + bz);
      float nn = tanhff(aIN[ftl][r] + bin + rr*(aHN[ftl][r] + bhn));
      float ho = bf2f(lds_in[cho + (qq*16 + nrow)*8 + jj]);
      float hv = (1.f - zz)*nn + zz*ho;
      lds_out[(wv*16 + nrow)*40 + kw] = f2bf(hv);
    }
  }
  __syncthreads();

  // write-back: 64 rows x 64 B (this block's 32-feat slice), 4 threads/row
  {
    int node = t >> 2, q4 = t & 3;
    int ng = nb + node;
    if (ng < NN){
      uint4 v = *(const uint4*)&lds_out[node*40 + q4*8];
      *(uint4*)&hout[(size_t)ng*HD + fg*32 + q4*8] = v;
    }
  }
}

// ---------------- local head: relu(hbf @ local_w^T + b) -> fp32 ----------------
__global__ __launch_bounds__(256) void local_gemm_mfma(
    const ushort* __restrict__ hbf, const ushort* __restrict__ lw_bf,
    const float* __restrict__ bias, float* __restrict__ local)
{
  int wv = threadIdx.x >> 6, lane = threadIdx.x & 63;
  int mt = blockIdx.x*4 + wv;
  if (mt >= NN/16) return;
  int m0 = mt*16, mrow = lane & 15, quad = lane >> 4;
  floatx4 acc[8] = {};
  for (int kc = 0; kc < 4; kc++){
    int k0 = kc*32 + quad*8;
    short8 a = load_frag(&hbf[(size_t)(m0 + mrow)*HD + k0]);
    #pragma unroll
    for (int ft = 0; ft < 8; ft++){
      short8 b = load_frag(&lw_bf[(size_t)(ft*16 + mrow)*HD + k0]);
      acc[ft] = MFMA(a, b, acc[ft]);
    }
  }
  #pragma unroll
  for (int ft = 0; ft < 8; ft++){
    float bv = bias[ft*16 + mrow];
    #pragma unroll
    for (int r = 0; r < 4; r++){
      int n = m0 + quad*4 + r;
      local[(size_t)n*HD + ft*16 + mrow] = fmaxf(acc[ft][r] + bv, 0.f);
    }
  }
}

// ---------------- segmented mean-pool (batch sorted, zero atomics) ----------------
__global__ __launch_bounds__(256) void pool_kernel(
    const float* __restrict__ local, const int* __restrict__ gptr,
    float* __restrict__ pooled)
{
  __shared__ float4 red[8][32];
  int g = blockIdx.x;
  int lane = threadIdx.x & 31;
  int st = threadIdx.x >> 5;
  int s0 = gptr[g], s1 = gptr[g+1];
  float4 acc = make_float4(0,0,0,0);
  for (int n = s0 + st; n < s1; n += 8){
    float4 v = *(const float4*)&local[(size_t)n*HD + lane*4];
    acc.x += v.x; acc.y += v.y; acc.z += v.z; acc.w += v.w;
  }
  red[st][lane] = acc;
  __syncthreads();
  if (st == 0){
    float4 s = red[0][lane];
    #pragma unroll
    for (int i=1;i<8;i++){
      float4 v = red[i][lane];
      s.x += v.x; s.y += v.y; s.z += v.z; s.w += v.w;
    }
    float cnt = (float)(s1 - s0);
    if (cnt < 1.0f) cnt = 1.0f;
    float inv = 1.0f / cnt;
    s.x *= inv; s.y *= inv; s.z *= inv; s.w *= inv;
    *(float4*)&pooled[g*HD + lane*4] = s;
  }
}

// ---------------- classifier + log_softmax ----------------
__global__ __launch_bounds__(64) void classifier_kernel(
    const float* __restrict__ pooled,
    const float* __restrict__ gw, const float* __restrict__ gb,
    float* __restrict__ out)
{
  int g = blockIdx.x;
  int lane = threadIdx.x;
  float p0 = pooled[g*HD + lane];
  float p1 = pooled[g*HD + 64 + lane];
  float vals[NC];
  #pragma unroll
  for (int c=0;c<NC;c++){
    float s = p0*gw[c*HD + lane] + p1*gw[c*HD + 64 + lane];
    #pragma unroll
    for (int off=32; off>0; off>>=1) s += __shfl_down(s, off, 64);
    vals[c] = s;
  }
  if (lane == 0){
    float mx = -1e30f;
    #pragma unroll
    for (int c=0;c<NC;c++){ vals[c] += gb[c]; mx = fmaxf(mx, vals[c]); }
    float se = 0.f;
    #pragma unroll
    for (int c=0;c<NC;c++) se += __expf(vals[c] - mx);
    float lse = mx + __logf(se);
    #pragma unroll
    for (int c=0;c<NC;c++) out[g*NC + c] = vals[c] - lse;
  }
}

extern "C" void kernel_launch(void* const* d_in, const int* in_sizes, int n_in,
                              void* d_out, int out_size, void* d_ws, size_t ws_size,
                              hipStream_t stream)
{
  const float* x        = (const float*)d_in[0];
  const int*   ei       = (const int*)  d_in[1];
  const int*   batch    = (const int*)  d_in[2];
  const float* W        = (const float*)d_in[3];
  const float* w_ih     = (const float*)d_in[4];
  const float* w_hh     = (const float*)d_in[5];
  const float* b_ih     = (const float*)d_in[6];
  const float* b_hh     = (const float*)d_in[7];
  const float* local_w  = (const float*)d_in[8];
  const float* local_b  = (const float*)d_in[9];
  const float* global_w = (const float*)d_in[10];
  const float* global_b = (const float*)d_in[11];
  float* out = (float*)d_out;

  // workspace layout
  char* base = (char*)d_ws;
  ushort* hB      = (ushort*)base;                    // 12.8 MB ping-pong h (B); pairs alias pre-layers
  uint*   pairs   = (uint*)base;                      //   3.2 MB (CSR build only, before layers)
  int*    bcur    = (int*)(base + 3200000);           //   50 KB  (CSR build only)
  char*   R       = base + 25600000;                  // 25.6 MB multi-use region
  ushort* sumh_bf = (ushort*)R;                       //   12.8 MB (live during layers)
  ushort* veffT   = (ushort*)(R + 12800000);          //   384 KB (live during layers)
  ushort* whh_bf  = (ushort*)(R + 13193216);          //   96 KB  (live during layers)
  float*  bsums   = (float*)(R + 13291520);           //   2 KB   (live during layers)
  float*  local   = (float*)R;                        //   25.6 MB (after layers; clobbers the above)
  ushort* xbf     = (ushort*)(base + 51200000);       // 12.8 MB
  ushort* hA      = (ushort*)(base + 64000000);       // 12.8 MB ping-pong h (A)
  ushort* lw_bf   = (ushort*)(base + 76800000);       // 32 KB
  float*  pooled  = (float*)(base + 76832768);        // 128 KB
  int* row_ptr    = (int*)(base + 76963840);          // NN+1
  int* deg        = row_ptr + (NN + 1);               // NN
  int* csr_src    = deg + NN;                         // NE
  int* gptr       = csr_src + NE;                     // NG+1
  int* bsum       = gptr + (NG + 1);                  // 49

  const int* esrc = ei;
  const int* edst = ei + NE;

  hipMemsetAsync(deg, 0, NN*sizeof(int), stream);
  prep_weights_bf16<<<259, 256, 0, stream>>>(w_hh, local_w, b_ih, b_hh, whh_bf, lw_bf, bsums);
  veff_kernel<<<768, 256, 0, stream>>>(W, w_ih, veffT);
  convert_x<<<6250, 256, 0, stream>>>((const float4*)x, (ushort4*)xbf);
  count_deg<<<3125, 256, 0, stream>>>(edst, deg);
  scan_blocks<<<49, 1024, 0, stream>>>(deg, row_ptr, bsum);
  scan_carry<<<1, 64, 0, stream>>>(bsum, row_ptr);
  scan_add<<<49, 1024, 0, stream>>>(bsum, row_ptr);
  bucket_init<<<49, 256, 0, stream>>>(row_ptr, bcur);
  fill_pairs<<<3125, 256, 0, stream>>>(esrc, edst, bcur, pairs);
  fill_csr_bucket<<<NBK, 64, 0, stream>>>(pairs, row_ptr, csr_src);
  graph_ptr_kernel<<<5, 64, 0, stream>>>(batch, gptr);

  // layers: aggregate (high-occ gather) then GRU (feat-split MFMA), ping-pong h
  const ushort* hin = xbf;
  ushort* houts[NL] = { hA, hB, hA, hB };
  for (int l = 0; l < NL; l++){
    aggregate_bf16<<<12500, 256, 0, stream>>>((const uint*)hin, row_ptr, csr_src, (uint*)sumh_bf);
    gru_mfma5<<<3128, 256, 0, stream>>>(sumh_bf, houts[l], hin,
                                        veffT + (size_t)l*49152, whh_bf, bsums);
    hin = houts[l];
  }

  local_gemm_mfma<<<782, 256, 0, stream>>>(hB, lw_bf, local_b, local);
  pool_kernel<<<NG, 256, 0, stream>>>(local, gptr, pooled);
  classifier_kernel<<<NG, 64, 0, stream>>>(pooled, global_w, global_b, out);
}

// Round 12
// 535.161 us; speedup vs baseline: 1.4863x; 1.3627x over previous
//
#include <hip/hip_runtime.h>

#define NN 50000
#define NE 800000
#define HD 128
#define NL 4
#define NC 10
#define NG 256
#define NBK 12500         // CSR buckets of 4 nodes (NN = 4*NBK exactly)

typedef __attribute__((ext_vector_type(8))) short short8;    // 8 bf16 = 4 VGPR (MFMA A/B frag)
typedef __attribute__((ext_vector_type(4))) float floatx4;   // MFMA C/D frag

union frg { uint4 u; short8 s; };

__device__ __forceinline__ short8 load_frag(const ushort* p){
  frg f; f.u = *(const uint4*)p; return f.s;
}
__device__ __forceinline__ floatx4 MFMA(short8 a, short8 b, floatx4 c){
  return __builtin_amdgcn_mfma_f32_16x16x32_bf16(a, b, c, 0, 0, 0);
}

__device__ __forceinline__ ushort f2bf(float x){           // RNE fp32->bf16
  unsigned u = __float_as_uint(x);
  return (ushort)((u + 0x7FFFu + ((u >> 16) & 1u)) >> 16);
}
__device__ __forceinline__ float bf2f(ushort b){
  return __uint_as_float(((uint)b) << 16);
}
__device__ __forceinline__ float sigmf(float x){ return 1.0f/(1.0f + __expf(-x)); }
__device__ __forceinline__ float tanhff(float x){ return 2.0f/(1.0f + __expf(-2.0f*x)) - 1.0f; }

// ---------------- prep: convert whh / local_w to bf16; fold biases ----------------
__global__ __launch_bounds__(256) void prep_weights_bf16(
    const float* __restrict__ w_hh, const float* __restrict__ local_w,
    const float* __restrict__ b_ih, const float* __restrict__ b_hh,
    ushort* __restrict__ whh_bf, ushort* __restrict__ lw_bf,
    float* __restrict__ bs)
{
  int idx = blockIdx.x*256 + threadIdx.x;
  if (idx < 49152) whh_bf[idx] = f2bf(w_hh[idx]);
  else if (idx < 65536){ int j = idx - 49152; lw_bf[j] = f2bf(local_w[j]); }
  else if (idx < 66048){
    int j = idx - 65536;       // 0..511: br(128), bz(128), bin(128), bhn(128)
    if (j < 256)      bs[j] = b_ih[j] + b_hh[j];
    else if (j < 384) bs[j] = b_ih[j];          // bin
    else              bs[j] = b_hh[j - 128];    // bhn
  }
}

// ---------------- Veff[l]^T[o][j] = sum_f W[l][j][f] * wih[o][f]  (fp32 acc -> bf16) ----------------
__global__ __launch_bounds__(256) void veff_kernel(
    const float* __restrict__ W, const float* __restrict__ w_ih,
    ushort* __restrict__ veffT)
{
  int idx = blockIdx.x*256 + threadIdx.x;    // l*49152 + o*128 + j
  if (idx >= 4*49152) return;
  int l = idx / 49152, rem = idx % 49152;
  int o = rem >> 7, j = rem & 127;
  const float4* wr = (const float4*)&W[(size_t)(l*128 + j)*128];
  const float4* ir = (const float4*)&w_ih[(size_t)o*128];
  float acc = 0.f;
  #pragma unroll
  for (int q = 0; q < 32; q++){
    float4 a = wr[q], b = ir[q];
    acc += a.x*b.x + a.y*b.y + a.z*b.z + a.w*b.w;
  }
  veffT[idx] = f2bf(acc);
}

__global__ __launch_bounds__(256) void convert_x(const float4* __restrict__ x, ushort4* __restrict__ xbf)
{
  int i = blockIdx.x*256 + threadIdx.x;
  if (i < NN*HD/4){
    float4 v = x[i];
    ushort4 o; o.x=f2bf(v.x); o.y=f2bf(v.y); o.z=f2bf(v.z); o.w=f2bf(v.w);
    xbf[i] = o;
  }
}

// ---------------- CSR build ----------------
__global__ __launch_bounds__(256) void count_deg(const int* __restrict__ dst, int* deg)
{
  int e = blockIdx.x*256 + threadIdx.x;
  if (e < NE){
    int d = __builtin_nontemporal_load(&dst[e]);
    atomicAdd(&deg[d], 1);
  }
}

__global__ __launch_bounds__(1024) void scan_blocks(
    const int* __restrict__ deg, int* __restrict__ excl_out, int* __restrict__ bsum)
{
  __shared__ int wsum[16];
  int t = threadIdx.x;
  int gid = blockIdx.x*1024 + t;
  int v = (gid < NN) ? deg[gid] : 0;
  int lane = t & 63, wv = t >> 6;
  int incl = v;
  #pragma unroll
  for (int off=1; off<64; off<<=1){
    int y = __shfl_up(incl, off, 64);
    if (lane >= off) incl += y;
  }
  if (lane == 63) wsum[wv] = incl;
  __syncthreads();
  if (wv == 0){
    int s = (lane < 16) ? wsum[lane] : 0;
    #pragma unroll
    for (int off=1; off<16; off<<=1){
      int y = __shfl_up(s, off, 64);
      if (lane >= off) s += y;
    }
    if (lane < 16) wsum[lane] = s;
  }
  __syncthreads();
  int wpre = (wv > 0) ? wsum[wv-1] : 0;
  if (gid < NN) excl_out[gid] = wpre + incl - v;
  if (t == 1023) bsum[blockIdx.x] = wpre + incl;
}

__global__ __launch_bounds__(64) void scan_carry(int* bsum, int* __restrict__ row_ptr)
{
  int lane = threadIdx.x;
  int v = (lane < 49) ? bsum[lane] : 0;
  int incl = v;
  #pragma unroll
  for (int off=1; off<64; off<<=1){
    int y = __shfl_up(incl, off, 64);
    if (lane >= off) incl += y;
  }
  if (lane < 49) bsum[lane] = incl - v;
  if (lane == 0) row_ptr[NN] = NE;
}

__global__ __launch_bounds__(1024) void scan_add(
    const int* __restrict__ bsum, int* __restrict__ row_ptr)
{
  int gid = blockIdx.x*1024 + threadIdx.x;
  if (gid < NN) row_ptr[gid] += bsum[blockIdx.x];
}

// bcur[b] = row_ptr[b*4]  (bucket write cursors for pair scatter)
__global__ __launch_bounds__(256) void bucket_init(const int* __restrict__ row_ptr, int* __restrict__ bcur)
{
  int b = blockIdx.x*256 + threadIdx.x;
  if (b < NBK) bcur[b] = row_ptr[b*4];
}

// Pass A: scatter packed (src | local_dst<<17) into 4-node bucket regions.
// 12500 tails keep atomic chains ~64 deep (round-8 lesson) and writes line-dense.
__global__ __launch_bounds__(256) void fill_pairs(
    const int* __restrict__ src, const int* __restrict__ dst,
    int* bcur, uint* __restrict__ pairs)
{
  int e = blockIdx.x*256 + threadIdx.x;
  if (e < NE){
    int s = __builtin_nontemporal_load(&src[e]);
    int d = __builtin_nontemporal_load(&dst[e]);
    int b = d >> 2;
    int pos = atomicAdd(&bcur[b], 1);
    pairs[pos] = (uint)s | ((uint)(d & 3) << 17);
  }
}

// Pass B: one wave per bucket; 4 per-node cursors in LDS.
__global__ __launch_bounds__(64) void fill_csr_bucket(
    const uint* __restrict__ pairs, const int* __restrict__ row_ptr,
    int* __restrict__ csr_src)
{
  __shared__ int lcur[4];
  int b = blockIdx.x;
  int n0 = b*4;
  int base = row_ptr[n0];
  int end  = row_ptr[n0+4];
  int t = threadIdx.x;
  if (t < 4) lcur[t] = row_ptr[n0 + t] - base;
  __syncthreads();
  for (int p = base + t; p < end; p += 64){
    uint pk = pairs[p];
    int ld = pk >> 17;
    int pos = atomicAdd(&lcur[ld], 1);
    csr_src[base + pos] = (int)(pk & 0x1FFFFu);
  }
}

__global__ __launch_bounds__(64) void graph_ptr_kernel(const int* __restrict__ batch, int* __restrict__ gptr)
{
  int g = blockIdx.x*64 + threadIdx.x;
  if (g > NG) return;
  int lo = 0, hi = NN;
  while (lo < hi){
    int mid = (lo + hi) >> 1;
    if (batch[mid] < g) lo = mid + 1; else hi = mid;
  }
  gptr[g] = lo;
}

// ---------------- K2: sumh[n] = sum_{e: dst=n} h[src]  (bf16 in, bf16 out) ----------------
// 2 nodes per wave: lanes 0-31 = node A, 32-63 = node B; 8 B/lane (uint2)
// -> 512 B payload per gather instruction (was 256), ~1.7x fewer issue slots.
// High-occupancy standalone kernel (round-10 lesson: never co-locate with MFMA).
__global__ __launch_bounds__(256) void aggregate_bf16(
    const uint2* __restrict__ m2, const int* __restrict__ row_ptr,
    const int* __restrict__ csr_src, uint2* __restrict__ aggr2)
{
  int t = threadIdx.x;
  int lane32 = t & 31;
  int nid = blockIdx.x*8 + (t >> 5);       // grid 6250 * 8 = 50000 exactly
  int s0 = row_ptr[nid], s1 = row_ptr[nid+1];
  float a0 = 0.f, a1 = 0.f, a2 = 0.f, a3 = 0.f;
  int j = s0;
  for (; j + 3 < s1; j += 4){
    int i0 = csr_src[j], i1 = csr_src[j+1], i2 = csr_src[j+2], i3 = csr_src[j+3];
    uint2 v0 = m2[(size_t)i0*32 + lane32];
    uint2 v1 = m2[(size_t)i1*32 + lane32];
    uint2 v2 = m2[(size_t)i2*32 + lane32];
    uint2 v3 = m2[(size_t)i3*32 + lane32];
    a0 += __uint_as_float(v0.x << 16) + __uint_as_float(v1.x << 16)
        + __uint_as_float(v2.x << 16) + __uint_as_float(v3.x << 16);
    a1 += __uint_as_float(v0.x & 0xFFFF0000u) + __uint_as_float(v1.x & 0xFFFF0000u)
        + __uint_as_float(v2.x & 0xFFFF0000u) + __uint_as_float(v3.x & 0xFFFF0000u);
    a2 += __uint_as_float(v0.y << 16) + __uint_as_float(v1.y << 16)
        + __uint_as_float(v2.y << 16) + __uint_as_float(v3.y << 16);
    a3 += __uint_as_float(v0.y & 0xFFFF0000u) + __uint_as_float(v1.y & 0xFFFF0000u)
        + __uint_as_float(v2.y & 0xFFFF0000u) + __uint_as_float(v3.y & 0xFFFF0000u);
  }
  for (; j < s1; j++){
    int s = csr_src[j];
    uint2 v = m2[(size_t)s*32 + lane32];
    a0 += __uint_as_float(v.x << 16);
    a1 += __uint_as_float(v.x & 0xFFFF0000u);
    a2 += __uint_as_float(v.y << 16);
    a3 += __uint_as_float(v.y & 0xFFFF0000u);
  }
  uint2 o;
  o.x = (uint)f2bf(a0) | ((uint)f2bf(a1) << 16);
  o.y = (uint)f2bf(a2) | ((uint)f2bf(a3) << 16);
  aggr2[(size_t)nid*32 + lane32] = o;
}

// ---------------- K3: fused GRU via MFMA; 64 nodes/block, 4x weight reuse ----------------
// (round-9 keeper: best of 5 probed GRU structures — do not re-split feats or fuse gather)
__global__ __launch_bounds__(256, 2) void gru_mfma4(
    const ushort* __restrict__ sumh_bf, ushort* __restrict__ h_bf_out,
    const ushort* __restrict__ h_bf_in,
    const ushort* __restrict__ veffT, const ushort* __restrict__ whh_bf,
    const float* __restrict__ bs)
{
  __shared__ __align__(16) ushort lds_in[16384];       // 32 KB: 32 chunks of 1 KB
  __shared__ __align__(16) ushort lds_out[64*136];     // 17 KB hv bf16, stride 136
  int t = threadIdx.x;
  int wv = t >> 6, lane = t & 63;
  int mrow = lane & 15, quad = lane >> 4;
  int nb = blockIdx.x * 64;

  #pragma unroll
  for (int q = 0; q < 8; q++){
    int c = wv*8 + q;                      // c = arr*16 + tt*4 + kc
    int arr = c >> 4, tt = (c >> 2) & 3, kc = c & 3;
    const ushort* srcb = arr ? h_bf_in : sumh_bf;
    int node = nb + tt*16 + mrow; if (node >= NN) node = NN-1;
    uint4 v = *(const uint4*)&srcb[(size_t)node*HD + kc*32 + quad*8];
    *(uint4*)&lds_in[c*512 + lane*8] = v;
  }
  __syncthreads();

  floatx4 aR[4][2] = {}, aZ[4][2] = {}, aIN[4][2] = {}, aHN[4][2] = {};

  #pragma unroll
  for (int kc = 0; kc < 4; kc++){
    int k0 = kc*32 + quad*8;
    short8 fa[4], fh[4];
    #pragma unroll
    for (int tt = 0; tt < 4; tt++){
      fa[tt] = load_frag(&lds_in[((tt<<2) | kc)*512 + lane*8]);
      fh[tt] = load_frag(&lds_in[(16 | (tt<<2) | kc)*512 + lane*8]);
    }
    #pragma unroll
    for (int ftl = 0; ftl < 2; ftl++){
      size_t wo = (size_t)((wv*2 + ftl)*16 + mrow)*HD + k0;
      short8 vir = load_frag(&veffT[wo]);
      short8 viz = load_frag(&veffT[128*HD + wo]);
      short8 vin = load_frag(&veffT[256*HD + wo]);
      short8 whr = load_frag(&whh_bf[wo]);
      short8 whz = load_frag(&whh_bf[128*HD + wo]);
      short8 whn = load_frag(&whh_bf[256*HD + wo]);
      #pragma unroll
      for (int tt = 0; tt < 4; tt++){
        aR[tt][ftl]  = MFMA(fa[tt], vir, aR[tt][ftl]);
        aR[tt][ftl]  = MFMA(fh[tt], whr, aR[tt][ftl]);
        aZ[tt][ftl]  = MFMA(fa[tt], viz, aZ[tt][ftl]);
        aZ[tt][ftl]  = MFMA(fh[tt], whz, aZ[tt][ftl]);
        aIN[tt][ftl] = MFMA(fa[tt], vin, aIN[tt][ftl]);
        aHN[tt][ftl] = MFMA(fh[tt], whn, aHN[tt][ftl]);
      }
    }
  }

  #pragma unroll
  for (int ftl = 0; ftl < 2; ftl++){
    int feat = wv*32 + ftl*16 + mrow;
    float br  = bs[feat], bz = bs[128+feat], bin = bs[256+feat], bhn = bs[384+feat];
    int kw = ftl*16 + mrow;
    int qq = kw >> 3, jj = kw & 7;
    #pragma unroll
    for (int tt = 0; tt < 4; tt++){
      int cho = (16 | (tt<<2) | wv)*512;         // h chunk, kc = wv
      #pragma unroll
      for (int r = 0; r < 4; r++){
        int nrow = quad*4 + r;
        float rr = sigmf(aR[tt][ftl][r] + br);
        float zz = sigmf(aZ[tt][ftl][r] + bz);
        float nn = tanhff(aIN[tt][ftl][r] + bin + rr*(aHN[tt][ftl][r] + bhn));
        float ho = bf2f(lds_in[cho + (qq*16 + nrow)*8 + jj]);
        float hv = (1.f - zz)*nn + zz*ho;
        lds_out[(tt*16 + nrow)*136 + feat] = f2bf(hv);
      }
    }
  }
  __syncthreads();

  #pragma unroll
  for (int p = 0; p < 4; p++){
    int chunk = p*256 + t;
    int node = chunk >> 4, f = (chunk & 15)*8;
    int ng = nb + node;
    if (ng < NN){
      uint4 v = *(const uint4*)&lds_out[node*136 + f];
      *(uint4*)&h_bf_out[(size_t)ng*HD + f] = v;
    }
  }
}

// ---------------- local head: relu(hbf @ local_w^T + b) -> fp32 ----------------
__global__ __launch_bounds__(256) void local_gemm_mfma(
    const ushort* __restrict__ hbf, const ushort* __restrict__ lw_bf,
    const float* __restrict__ bias, float* __restrict__ local)
{
  int wv = threadIdx.x >> 6, lane = threadIdx.x & 63;
  int mt = blockIdx.x*4 + wv;
  if (mt >= NN/16) return;
  int m0 = mt*16, mrow = lane & 15, quad = lane >> 4;
  floatx4 acc[8] = {};
  for (int kc = 0; kc < 4; kc++){
    int k0 = kc*32 + quad*8;
    short8 a = load_frag(&hbf[(size_t)(m0 + mrow)*HD + k0]);
    #pragma unroll
    for (int ft = 0; ft < 8; ft++){
      short8 b = load_frag(&lw_bf[(size_t)(ft*16 + mrow)*HD + k0]);
      acc[ft] = MFMA(a, b, acc[ft]);
    }
  }
  #pragma unroll
  for (int ft = 0; ft < 8; ft++){
    float bv = bias[ft*16 + mrow];
    #pragma unroll
    for (int r = 0; r < 4; r++){
      int n = m0 + quad*4 + r;
      local[(size_t)n*HD + ft*16 + mrow] = fmaxf(acc[ft][r] + bv, 0.f);
    }
  }
}

// ---------------- segmented mean-pool (batch sorted, zero atomics) ----------------
__global__ __launch_bounds__(256) void pool_kernel(
    const float* __restrict__ local, const int* __restrict__ gptr,
    float* __restrict__ pooled)
{
  __shared__ float4 red[8][32];
  int g = blockIdx.x;
  int lane = threadIdx.x & 31;
  int st = threadIdx.x >> 5;
  int s0 = gptr[g], s1 = gptr[g+1];
  float4 acc = make_float4(0,0,0,0);
  for (int n = s0 + st; n < s1; n += 8){
    float4 v = *(const float4*)&local[(size_t)n*HD + lane*4];
    acc.x += v.x; acc.y += v.y; acc.z += v.z; acc.w += v.w;
  }
  red[st][lane] = acc;
  __syncthreads();
  if (st == 0){
    float4 s = red[0][lane];
    #pragma unroll
    for (int i=1;i<8;i++){
      float4 v = red[i][lane];
      s.x += v.x; s.y += v.y; s.z += v.z; s.w += v.w;
    }
    float cnt = (float)(s1 - s0);
    if (cnt < 1.0f) cnt = 1.0f;
    float inv = 1.0f / cnt;
    s.x *= inv; s.y *= inv; s.z *= inv; s.w *= inv;
    *(float4*)&pooled[g*HD + lane*4] = s;
  }
}

// ---------------- classifier + log_softmax ----------------
__global__ __launch_bounds__(64) void classifier_kernel(
    const float* __restrict__ pooled,
    const float* __restrict__ gw, const float* __restrict__ gb,
    float* __restrict__ out)
{
  int g = blockIdx.x;
  int lane = threadIdx.x;
  float p0 = pooled[g*HD + lane];
  float p1 = pooled[g*HD + 64 + lane];
  float vals[NC];
  #pragma unroll
  for (int c=0;c<NC;c++){
    float s = p0*gw[c*HD + lane] + p1*gw[c*HD + 64 + lane];
    #pragma unroll
    for (int off=32; off>0; off>>=1) s += __shfl_down(s, off, 64);
    vals[c] = s;
  }
  if (lane == 0){
    float mx = -1e30f;
    #pragma unroll
    for (int c=0;c<NC;c++){ vals[c] += gb[c]; mx = fmaxf(mx, vals[c]); }
    float se = 0.f;
    #pragma unroll
    for (int c=0;c<NC;c++) se += __expf(vals[c] - mx);
    float lse = mx + __logf(se);
    #pragma unroll
    for (int c=0;c<NC;c++) out[g*NC + c] = vals[c] - lse;
  }
}

extern "C" void kernel_launch(void* const* d_in, const int* in_sizes, int n_in,
                              void* d_out, int out_size, void* d_ws, size_t ws_size,
                              hipStream_t stream)
{
  const float* x        = (const float*)d_in[0];
  const int*   ei       = (const int*)  d_in[1];
  const int*   batch    = (const int*)  d_in[2];
  const float* W        = (const float*)d_in[3];
  const float* w_ih     = (const float*)d_in[4];
  const float* w_hh     = (const float*)d_in[5];
  const float* b_ih     = (const float*)d_in[6];
  const float* b_hh     = (const float*)d_in[7];
  const float* local_w  = (const float*)d_in[8];
  const float* local_b  = (const float*)d_in[9];
  const float* global_w = (const float*)d_in[10];
  const float* global_b = (const float*)d_in[11];
  float* out = (float*)d_out;

  // workspace layout (round-9 layout)
  char* base = (char*)d_ws;
  uint*   pairs   = (uint*)base;                      // 3.2 MB (CSR build only)
  int*    bcur    = (int*)(base + 3200000);           // 50 KB  (CSR build only)
  char*   R       = base + 25600000;                  // 25.6 MB multi-use region
  ushort* sumh_bf = (ushort*)R;                       //   12.8 MB (live during layers)
  ushort* veffT   = (ushort*)(R + 12800000);          //   384 KB (live during layers)
  ushort* whh_bf  = (ushort*)(R + 13193216);          //   96 KB  (live during layers)
  float*  bsums   = (float*)(R + 13291520);           //   2 KB   (live during layers)
  float*  local   = (float*)R;                        //   25.6 MB (after layers)
  ushort* xbf     = (ushort*)(base + 51200000);       // 12.8 MB
  ushort* hbf     = (ushort*)(base + 64000000);       // 12.8 MB
  ushort* lw_bf   = (ushort*)(base + 76800000);       // 32 KB
  float*  pooled  = (float*)(base + 76832768);        // 128 KB
  int* row_ptr    = (int*)(base + 76963840);          // NN+1
  int* deg        = row_ptr + (NN + 1);               // NN
  int* csr_src    = deg + NN;                         // NE
  int* gptr       = csr_src + NE;                     // NG+1
  int* bsum       = gptr + (NG + 1);                  // 49

  const int* esrc = ei;
  const int* edst = ei + NE;

  hipMemsetAsync(deg, 0, NN*sizeof(int), stream);
  prep_weights_bf16<<<259, 256, 0, stream>>>(w_hh, local_w, b_ih, b_hh, whh_bf, lw_bf, bsums);
  veff_kernel<<<768, 256, 0, stream>>>(W, w_ih, veffT);
  convert_x<<<6250, 256, 0, stream>>>((const float4*)x, (ushort4*)xbf);
  count_deg<<<3125, 256, 0, stream>>>(edst, deg);
  scan_blocks<<<49, 1024, 0, stream>>>(deg, row_ptr, bsum);
  scan_carry<<<1, 64, 0, stream>>>(bsum, row_ptr);
  scan_add<<<49, 1024, 0, stream>>>(bsum, row_ptr);
  bucket_init<<<49, 256, 0, stream>>>(row_ptr, bcur);
  fill_pairs<<<3125, 256, 0, stream>>>(esrc, edst, bcur, pairs);
  fill_csr_bucket<<<NBK, 64, 0, stream>>>(pairs, row_ptr, csr_src);
  graph_ptr_kernel<<<5, 64, 0, stream>>>(batch, gptr);

  // layers: high-occ gather, then 64-node full-feat MFMA GRU (in-place hbf after layer 0)
  const ushort* hin_b = xbf;
  for (int l = 0; l < NL; l++){
    aggregate_bf16<<<6250, 256, 0, stream>>>((const uint2*)hin_b, row_ptr, csr_src, (uint2*)sumh_bf);
    gru_mfma4<<<782, 256, 0, stream>>>(sumh_bf, hbf, hin_b,
                                       veffT + (size_t)l*49152, whh_bf, bsums);
    hin_b = hbf;
  }

  local_gemm_mfma<<<782, 256, 0, stream>>>(hbf, lw_bf, local_b, local);
  pool_kernel<<<NG, 256, 0, stream>>>(local, gptr, pooled);
  classifier_kernel<<<NG, 64, 0, stream>>>(pooled, global_w, global_b, out);
}

// Round 13
// 489.517 us; speedup vs baseline: 1.6249x; 1.0932x over previous
//
#include <hip/hip_runtime.h>

#define NN 50000
#define NE 800000
#define HD 128
#define NL 4
#define NC 10
#define NG 256
#define CAP 64            // fixed slots per node; deg ~ Poisson(16), P(deg>64) < 1e-20

typedef __attribute__((ext_vector_type(8))) short short8;    // 8 bf16 = 4 VGPR (MFMA A/B frag)
typedef __attribute__((ext_vector_type(4))) float floatx4;   // MFMA C/D frag

union frg { uint4 u; short8 s; };

__device__ __forceinline__ short8 load_frag(const ushort* p){
  frg f; f.u = *(const uint4*)p; return f.s;
}
__device__ __forceinline__ floatx4 MFMA(short8 a, short8 b, floatx4 c){
  return __builtin_amdgcn_mfma_f32_16x16x32_bf16(a, b, c, 0, 0, 0);
}

__device__ __forceinline__ ushort f2bf(float x){           // RNE fp32->bf16
  unsigned u = __float_as_uint(x);
  return (ushort)((u + 0x7FFFu + ((u >> 16) & 1u)) >> 16);
}
__device__ __forceinline__ float bf2f(ushort b){
  return __uint_as_float(((uint)b) << 16);
}
__device__ __forceinline__ float sigmf(float x){ return 1.0f/(1.0f + __expf(-x)); }
__device__ __forceinline__ float tanhff(float x){ return 2.0f/(1.0f + __expf(-2.0f*x)) - 1.0f; }

// ---------------- prep: convert whh / local_w to bf16; fold biases ----------------
__global__ __launch_bounds__(256) void prep_weights_bf16(
    const float* __restrict__ w_hh, const float* __restrict__ local_w,
    const float* __restrict__ b_ih, const float* __restrict__ b_hh,
    ushort* __restrict__ whh_bf, ushort* __restrict__ lw_bf,
    float* __restrict__ bs)
{
  int idx = blockIdx.x*256 + threadIdx.x;
  if (idx < 49152) whh_bf[idx] = f2bf(w_hh[idx]);
  else if (idx < 65536){ int j = idx - 49152; lw_bf[j] = f2bf(local_w[j]); }
  else if (idx < 66048){
    int j = idx - 65536;       // 0..511: br(128), bz(128), bin(128), bhn(128)
    if (j < 256)      bs[j] = b_ih[j] + b_hh[j];
    else if (j < 384) bs[j] = b_ih[j];          // bin
    else              bs[j] = b_hh[j - 128];    // bhn
  }
}

// ---------------- Veff[l]^T[o][j] = sum_f W[l][j][f] * wih[o][f]  (fp32 acc -> bf16) ----------------
__global__ __launch_bounds__(256) void veff_kernel(
    const float* __restrict__ W, const float* __restrict__ w_ih,
    ushort* __restrict__ veffT)
{
  int idx = blockIdx.x*256 + threadIdx.x;    // l*49152 + o*128 + j
  if (idx >= 4*49152) return;
  int l = idx / 49152, rem = idx % 49152;
  int o = rem >> 7, j = rem & 127;
  const float4* wr = (const float4*)&W[(size_t)(l*128 + j)*128];
  const float4* ir = (const float4*)&w_ih[(size_t)o*128];
  float acc = 0.f;
  #pragma unroll
  for (int q = 0; q < 32; q++){
    float4 a = wr[q], b = ir[q];
    acc += a.x*b.x + a.y*b.y + a.z*b.z + a.w*b.w;
  }
  veffT[idx] = f2bf(acc);
}

__global__ __launch_bounds__(256) void convert_x(const float4* __restrict__ x, ushort4* __restrict__ xbf)
{
  int i = blockIdx.x*256 + threadIdx.x;
  if (i < NN*HD/4){
    float4 v = x[i];
    ushort4 o; o.x=f2bf(v.x); o.y=f2bf(v.y); o.z=f2bf(v.z); o.w=f2bf(v.w);
    xbf[i] = o;
  }
}

// ---------------- CSR build: ONE pass, fixed-capacity rows ----------------
// pos = atomicAdd(deg[d]) (16-deep chains, cheap per r8/r12 data); direct scatter into
// csr_fixed[d*64+pos]. Replaces count+scan+bucket_init+fill_pairs+fill_csr_bucket
// (scatter-write inflation ~45MB is irreducible — pay it once, drop the other passes).
__global__ __launch_bounds__(256) void fill_csr_direct(
    const int* __restrict__ src, const int* __restrict__ dst,
    int* deg, int* __restrict__ csrf)
{
  int e = blockIdx.x*256 + threadIdx.x;
  if (e < NE){
    int s = __builtin_nontemporal_load(&src[e]);
    int d = __builtin_nontemporal_load(&dst[e]);
    int pos = atomicAdd(&deg[d], 1);
    if (pos < CAP) csrf[(d << 6) + pos] = s;
  }
}

__global__ __launch_bounds__(64) void graph_ptr_kernel(const int* __restrict__ batch, int* __restrict__ gptr)
{
  int g = blockIdx.x*64 + threadIdx.x;
  if (g > NG) return;
  int lo = 0, hi = NN;
  while (lo < hi){
    int mid = (lo + hi) >> 1;
    if (batch[mid] < g) lo = mid + 1; else hi = mid;
  }
  gptr[g] = lo;
}

// ---------------- K2: sumh[n] = sum over fixed-capacity edge list of h[src] ----------------
// 2 nodes per wave (half-waves, uint2 = 8 B/lane): 512 B payload per gather instruction.
// High-occupancy standalone kernel (round-10 lesson: never co-locate with MFMA).
__global__ __launch_bounds__(256) void aggregate_bf16(
    const uint2* __restrict__ m2, const int* __restrict__ deg,
    const int* __restrict__ csrf, uint2* __restrict__ aggr2)
{
  int t = threadIdx.x;
  int lane32 = t & 31;
  int nid = blockIdx.x*8 + (t >> 5);       // grid 6250 * 8 = 50000 exactly
  int cnt = deg[nid]; if (cnt > CAP) cnt = CAP;
  const int* lst = csrf + (nid << 6);
  float a0 = 0.f, a1 = 0.f, a2 = 0.f, a3 = 0.f;
  int j = 0;
  for (; j + 3 < cnt; j += 4){
    int i0 = lst[j], i1 = lst[j+1], i2 = lst[j+2], i3 = lst[j+3];
    uint2 v0 = m2[(size_t)i0*32 + lane32];
    uint2 v1 = m2[(size_t)i1*32 + lane32];
    uint2 v2 = m2[(size_t)i2*32 + lane32];
    uint2 v3 = m2[(size_t)i3*32 + lane32];
    a0 += __uint_as_float(v0.x << 16) + __uint_as_float(v1.x << 16)
        + __uint_as_float(v2.x << 16) + __uint_as_float(v3.x << 16);
    a1 += __uint_as_float(v0.x & 0xFFFF0000u) + __uint_as_float(v1.x & 0xFFFF0000u)
        + __uint_as_float(v2.x & 0xFFFF0000u) + __uint_as_float(v3.x & 0xFFFF0000u);
    a2 += __uint_as_float(v0.y << 16) + __uint_as_float(v1.y << 16)
        + __uint_as_float(v2.y << 16) + __uint_as_float(v3.y << 16);
    a3 += __uint_as_float(v0.y & 0xFFFF0000u) + __uint_as_float(v1.y & 0xFFFF0000u)
        + __uint_as_float(v2.y & 0xFFFF0000u) + __uint_as_float(v3.y & 0xFFFF0000u);
  }
  for (; j < cnt; j++){
    int s = lst[j];
    uint2 v = m2[(size_t)s*32 + lane32];
    a0 += __uint_as_float(v.x << 16);
    a1 += __uint_as_float(v.x & 0xFFFF0000u);
    a2 += __uint_as_float(v.y << 16);
    a3 += __uint_as_float(v.y & 0xFFFF0000u);
  }
  uint2 o;
  o.x = (uint)f2bf(a0) | ((uint)f2bf(a1) << 16);
  o.y = (uint)f2bf(a2) | ((uint)f2bf(a3) << 16);
  aggr2[(size_t)nid*32 + lane32] = o;
}

// ---------------- K3: fused GRU via MFMA; 64 nodes/block, 4x weight reuse ----------------
// (round-9 keeper: best of 5 probed GRU structures — do not re-split feats or fuse gather)
__global__ __launch_bounds__(256, 2) void gru_mfma4(
    const ushort* __restrict__ sumh_bf, ushort* __restrict__ h_bf_out,
    const ushort* __restrict__ h_bf_in,
    const ushort* __restrict__ veffT, const ushort* __restrict__ whh_bf,
    const float* __restrict__ bs)
{
  __shared__ __align__(16) ushort lds_in[16384];       // 32 KB: 32 chunks of 1 KB
  __shared__ __align__(16) ushort lds_out[64*136];     // 17 KB hv bf16, stride 136
  int t = threadIdx.x;
  int wv = t >> 6, lane = t & 63;
  int mrow = lane & 15, quad = lane >> 4;
  int nb = blockIdx.x * 64;

  #pragma unroll
  for (int q = 0; q < 8; q++){
    int c = wv*8 + q;                      // c = arr*16 + tt*4 + kc
    int arr = c >> 4, tt = (c >> 2) & 3, kc = c & 3;
    const ushort* srcb = arr ? h_bf_in : sumh_bf;
    int node = nb + tt*16 + mrow; if (node >= NN) node = NN-1;
    uint4 v = *(const uint4*)&srcb[(size_t)node*HD + kc*32 + quad*8];
    *(uint4*)&lds_in[c*512 + lane*8] = v;
  }
  __syncthreads();

  floatx4 aR[4][2] = {}, aZ[4][2] = {}, aIN[4][2] = {}, aHN[4][2] = {};

  #pragma unroll
  for (int kc = 0; kc < 4; kc++){
    int k0 = kc*32 + quad*8;
    short8 fa[4], fh[4];
    #pragma unroll
    for (int tt = 0; tt < 4; tt++){
      fa[tt] = load_frag(&lds_in[((tt<<2) | kc)*512 + lane*8]);
      fh[tt] = load_frag(&lds_in[(16 | (tt<<2) | kc)*512 + lane*8]);
    }
    #pragma unroll
    for (int ftl = 0; ftl < 2; ftl++){
      size_t wo = (size_t)((wv*2 + ftl)*16 + mrow)*HD + k0;
      short8 vir = load_frag(&veffT[wo]);
      short8 viz = load_frag(&veffT[128*HD + wo]);
      short8 vin = load_frag(&veffT[256*HD + wo]);
      short8 whr = load_frag(&whh_bf[wo]);
      short8 whz = load_frag(&whh_bf[128*HD + wo]);
      short8 whn = load_frag(&whh_bf[256*HD + wo]);
      #pragma unroll
      for (int tt = 0; tt < 4; tt++){
        aR[tt][ftl]  = MFMA(fa[tt], vir, aR[tt][ftl]);
        aR[tt][ftl]  = MFMA(fh[tt], whr, aR[tt][ftl]);
        aZ[tt][ftl]  = MFMA(fa[tt], viz, aZ[tt][ftl]);
        aZ[tt][ftl]  = MFMA(fh[tt], whz, aZ[tt][ftl]);
        aIN[tt][ftl] = MFMA(fa[tt], vin, aIN[tt][ftl]);
        aHN[tt][ftl] = MFMA(fh[tt], whn, aHN[tt][ftl]);
      }
    }
  }

  #pragma unroll
  for (int ftl = 0; ftl < 2; ftl++){
    int feat = wv*32 + ftl*16 + mrow;
    float br  = bs[feat], bz = bs[128+feat], bin = bs[256+feat], bhn = bs[384+feat];
    int kw = ftl*16 + mrow;
    int qq = kw >> 3, jj = kw & 7;
    #pragma unroll
    for (int tt = 0; tt < 4; tt++){
      int cho = (16 | (tt<<2) | wv)*512;         // h chunk, kc = wv
      #pragma unroll
      for (int r = 0; r < 4; r++){
        int nrow = quad*4 + r;
        float rr = sigmf(aR[tt][ftl][r] + br);
        float zz = sigmf(aZ[tt][ftl][r] + bz);
        float nn = tanhff(aIN[tt][ftl][r] + bin + rr*(aHN[tt][ftl][r] + bhn));
        float ho = bf2f(lds_in[cho + (qq*16 + nrow)*8 + jj]);
        float hv = (1.f - zz)*nn + zz*ho;
        lds_out[(tt*16 + nrow)*136 + feat] = f2bf(hv);
      }
    }
  }
  __syncthreads();

  #pragma unroll
  for (int p = 0; p < 4; p++){
    int chunk = p*256 + t;
    int node = chunk >> 4, f = (chunk & 15)*8;
    int ng = nb + node;
    if (ng < NN){
      uint4 v = *(const uint4*)&lds_out[node*136 + f];
      *(uint4*)&h_bf_out[(size_t)ng*HD + f] = v;
    }
  }
}

// ---------------- local head: relu(hbf @ local_w^T + b) -> fp32 ----------------
__global__ __launch_bounds__(256) void local_gemm_mfma(
    const ushort* __restrict__ hbf, const ushort* __restrict__ lw_bf,
    const float* __restrict__ bias, float* __restrict__ local)
{
  int wv = threadIdx.x >> 6, lane = threadIdx.x & 63;
  int mt = blockIdx.x*4 + wv;
  if (mt >= NN/16) return;
  int m0 = mt*16, mrow = lane & 15, quad = lane >> 4;
  floatx4 acc[8] = {};
  for (int kc = 0; kc < 4; kc++){
    int k0 = kc*32 + quad*8;
    short8 a = load_frag(&hbf[(size_t)(m0 + mrow)*HD + k0]);
    #pragma unroll
    for (int ft = 0; ft < 8; ft++){
      short8 b = load_frag(&lw_bf[(size_t)(ft*16 + mrow)*HD + k0]);
      acc[ft] = MFMA(a, b, acc[ft]);
    }
  }
  #pragma unroll
  for (int ft = 0; ft < 8; ft++){
    float bv = bias[ft*16 + mrow];
    #pragma unroll
    for (int r = 0; r < 4; r++){
      int n = m0 + quad*4 + r;
      local[(size_t)n*HD + ft*16 + mrow] = fmaxf(acc[ft][r] + bv, 0.f);
    }
  }
}

// ---------------- segmented mean-pool (batch sorted, zero atomics) ----------------
__global__ __launch_bounds__(256) void pool_kernel(
    const float* __restrict__ local, const int* __restrict__ gptr,
    float* __restrict__ pooled)
{
  __shared__ float4 red[8][32];
  int g = blockIdx.x;
  int lane = threadIdx.x & 31;
  int st = threadIdx.x >> 5;
  int s0 = gptr[g], s1 = gptr[g+1];
  float4 acc = make_float4(0,0,0,0);
  for (int n = s0 + st; n < s1; n += 8){
    float4 v = *(const float4*)&local[(size_t)n*HD + lane*4];
    acc.x += v.x; acc.y += v.y; acc.z += v.z; acc.w += v.w;
  }
  red[st][lane] = acc;
  __syncthreads();
  if (st == 0){
    float4 s = red[0][lane];
    #pragma unroll
    for (int i=1;i<8;i++){
      float4 v = red[i][lane];
      s.x += v.x; s.y += v.y; s.z += v.z; s.w += v.w;
    }
    float cnt = (float)(s1 - s0);
    if (cnt < 1.0f) cnt = 1.0f;
    float inv = 1.0f / cnt;
    s.x *= inv; s.y *= inv; s.z *= inv; s.w *= inv;
    *(float4*)&pooled[g*HD + lane*4] = s;
  }
}

// ---------------- classifier + log_softmax ----------------
__global__ __launch_bounds__(64) void classifier_kernel(
    const float* __restrict__ pooled,
    const float* __restrict__ gw, const float* __restrict__ gb,
    float* __restrict__ out)
{
  int g = blockIdx.x;
  int lane = threadIdx.x;
  float p0 = pooled[g*HD + lane];
  float p1 = pooled[g*HD + 64 + lane];
  float vals[NC];
  #pragma unroll
  for (int c=0;c<NC;c++){
    float s = p0*gw[c*HD + lane] + p1*gw[c*HD + 64 + lane];
    #pragma unroll
    for (int off=32; off>0; off>>=1) s += __shfl_down(s, off, 64);
    vals[c] = s;
  }
  if (lane == 0){
    float mx = -1e30f;
    #pragma unroll
    for (int c=0;c<NC;c++){ vals[c] += gb[c]; mx = fmaxf(mx, vals[c]); }
    float se = 0.f;
    #pragma unroll
    for (int c=0;c<NC;c++) se += __expf(vals[c] - mx);
    float lse = mx + __logf(se);
    #pragma unroll
    for (int c=0;c<NC;c++) out[g*NC + c] = vals[c] - lse;
  }
}

extern "C" void kernel_launch(void* const* d_in, const int* in_sizes, int n_in,
                              void* d_out, int out_size, void* d_ws, size_t ws_size,
                              hipStream_t stream)
{
  const float* x        = (const float*)d_in[0];
  const int*   ei       = (const int*)  d_in[1];
  const int*   batch    = (const int*)  d_in[2];
  const float* W        = (const float*)d_in[3];
  const float* w_ih     = (const float*)d_in[4];
  const float* w_hh     = (const float*)d_in[5];
  const float* b_ih     = (const float*)d_in[6];
  const float* b_hh     = (const float*)d_in[7];
  const float* local_w  = (const float*)d_in[8];
  const float* local_b  = (const float*)d_in[9];
  const float* global_w = (const float*)d_in[10];
  const float* global_b = (const float*)d_in[11];
  float* out = (float*)d_out;

  // workspace layout
  char* base = (char*)d_ws;
  char*   R       = base + 25600000;                  // 25.6 MB multi-use region
  ushort* sumh_bf = (ushort*)R;                       //   12.8 MB (live during layers)
  ushort* veffT   = (ushort*)(R + 12800000);          //   384 KB (live during layers)
  ushort* whh_bf  = (ushort*)(R + 13193216);          //   96 KB  (live during layers)
  float*  bsums   = (float*)(R + 13291520);           //   2 KB   (live during layers)
  float*  local   = (float*)R;                        //   25.6 MB (after layers)
  ushort* xbf     = (ushort*)(base + 51200000);       // 12.8 MB
  ushort* hbf     = (ushort*)(base + 64000000);       // 12.8 MB
  ushort* lw_bf   = (ushort*)(base + 76800000);       // 32 KB
  float*  pooled  = (float*)(base + 76832768);        // 128 KB
  int* deg        = (int*)(base + 76963840);          // NN
  int* gptr       = deg + NN;                         // NG+1
  int* csr_fixed  = (int*)base;                       // NN*64 ints = 12.8 MB (first region, CSR-build + layers; freed after layers? no — used all layers. NOTE: overlaps nothing: first 25.6 MB region only holds csr_fixed)

  const int* esrc = ei;
  const int* edst = ei + NE;

  hipMemsetAsync(deg, 0, NN*sizeof(int), stream);
  prep_weights_bf16<<<259, 256, 0, stream>>>(w_hh, local_w, b_ih, b_hh, whh_bf, lw_bf, bsums);
  veff_kernel<<<768, 256, 0, stream>>>(W, w_ih, veffT);
  convert_x<<<6250, 256, 0, stream>>>((const float4*)x, (ushort4*)xbf);
  fill_csr_direct<<<3125, 256, 0, stream>>>(esrc, edst, deg, csr_fixed);
  graph_ptr_kernel<<<5, 64, 0, stream>>>(batch, gptr);

  // layers: high-occ gather, then 64-node full-feat MFMA GRU (in-place hbf after layer 0)
  const ushort* hin_b = xbf;
  for (int l = 0; l < NL; l++){
    aggregate_bf16<<<6250, 256, 0, stream>>>((const uint2*)hin_b, deg, csr_fixed, (uint2*)sumh_bf);
    gru_mfma4<<<782, 256, 0, stream>>>(sumh_bf, hbf, hin_b,
                                       veffT + (size_t)l*49152, whh_bf, bsums);
    hin_b = hbf;
  }

  local_gemm_mfma<<<782, 256, 0, stream>>>(hbf, lw_bf, local_b, local);
  pool_kernel<<<NG, 256, 0, stream>>>(local, gptr, pooled);
  classifier_kernel<<<NG, 64, 0, stream>>>(pooled, global_w, global_b, out);
}

// Round 14
// 480.846 us; speedup vs baseline: 1.6542x; 1.0180x over previous
//
#include <hip/hip_runtime.h>

#define NN 50000
#define NE 800000
#define HD 128
#define NL 4
#define NC 10
#define NG 256
#define CAP 64            // fixed slots per node; deg ~ Poisson(16), P(deg>64) < 1e-20

typedef __attribute__((ext_vector_type(8))) short short8;    // 8 bf16 = 4 VGPR (MFMA A/B frag)
typedef __attribute__((ext_vector_type(4))) float floatx4;   // MFMA C/D frag

union frg { uint4 u; short8 s; };

__device__ __forceinline__ short8 load_frag(const ushort* p){
  frg f; f.u = *(const uint4*)p; return f.s;
}
__device__ __forceinline__ floatx4 MFMA(short8 a, short8 b, floatx4 c){
  return __builtin_amdgcn_mfma_f32_16x16x32_bf16(a, b, c, 0, 0, 0);
}

__device__ __forceinline__ ushort f2bf(float x){           // RNE fp32->bf16
  unsigned u = __float_as_uint(x);
  return (ushort)((u + 0x7FFFu + ((u >> 16) & 1u)) >> 16);
}
__device__ __forceinline__ float bf2f(ushort b){
  return __uint_as_float(((uint)b) << 16);
}
__device__ __forceinline__ float sigmf(float x){ return 1.0f/(1.0f + __expf(-x)); }
__device__ __forceinline__ float tanhff(float x){ return 2.0f/(1.0f + __expf(-2.0f*x)) - 1.0f; }

// ---------------- prep: convert whh / local_w to bf16; fold biases ----------------
__global__ __launch_bounds__(256) void prep_weights_bf16(
    const float* __restrict__ w_hh, const float* __restrict__ local_w,
    const float* __restrict__ b_ih, const float* __restrict__ b_hh,
    ushort* __restrict__ whh_bf, ushort* __restrict__ lw_bf,
    float* __restrict__ bs)
{
  int idx = blockIdx.x*256 + threadIdx.x;
  if (idx < 49152) whh_bf[idx] = f2bf(w_hh[idx]);
  else if (idx < 65536){ int j = idx - 49152; lw_bf[j] = f2bf(local_w[j]); }
  else if (idx < 66048){
    int j = idx - 65536;       // 0..511: br(128), bz(128), bin(128), bhn(128)
    if (j < 256)      bs[j] = b_ih[j] + b_hh[j];
    else if (j < 384) bs[j] = b_ih[j];          // bin
    else              bs[j] = b_hh[j - 128];    // bhn
  }
}

// ---------------- Veff[l]^T[o][j] = sum_f W[l][j][f] * wih[o][f]  (fp32 acc -> bf16) ----------------
__global__ __launch_bounds__(256) void veff_kernel(
    const float* __restrict__ W, const float* __restrict__ w_ih,
    ushort* __restrict__ veffT)
{
  int idx = blockIdx.x*256 + threadIdx.x;    // l*49152 + o*128 + j
  if (idx >= 4*49152) return;
  int l = idx / 49152, rem = idx % 49152;
  int o = rem >> 7, j = rem & 127;
  const float4* wr = (const float4*)&W[(size_t)(l*128 + j)*128];
  const float4* ir = (const float4*)&w_ih[(size_t)o*128];
  float acc = 0.f;
  #pragma unroll
  for (int q = 0; q < 32; q++){
    float4 a = wr[q], b = ir[q];
    acc += a.x*b.x + a.y*b.y + a.z*b.z + a.w*b.w;
  }
  veffT[idx] = f2bf(acc);
}

__global__ __launch_bounds__(256) void convert_x(const float4* __restrict__ x, ushort4* __restrict__ xbf)
{
  int i = blockIdx.x*256 + threadIdx.x;
  if (i < NN*HD/4){
    float4 v = x[i];
    ushort4 o; o.x=f2bf(v.x); o.y=f2bf(v.y); o.z=f2bf(v.z); o.w=f2bf(v.w);
    xbf[i] = o;
  }
}

// ---------------- CSR build: ONE pass, fixed-capacity rows ----------------
// pos = atomicAdd(deg[d]) (16-deep chains, cheap); direct scatter into csrf[d*64+pos].
// ~48MB write (partial-line evictions) at ~1TB/s = ~50us: probed scatter floor
// (r7 50us / r8 281us / r9 55us / r13 50us) — accepted.
__global__ __launch_bounds__(256) void fill_csr_direct(
    const int* __restrict__ src, const int* __restrict__ dst,
    int* deg, int* __restrict__ csrf)
{
  int e = blockIdx.x*256 + threadIdx.x;
  if (e < NE){
    int s = __builtin_nontemporal_load(&src[e]);
    int d = __builtin_nontemporal_load(&dst[e]);
    int pos = atomicAdd(&deg[d], 1);
    if (pos < CAP) csrf[(d << 6) + pos] = s;
  }
}

__global__ __launch_bounds__(64) void graph_ptr_kernel(const int* __restrict__ batch, int* __restrict__ gptr)
{
  int g = blockIdx.x*64 + threadIdx.x;
  if (g > NG) return;
  int lo = 0, hi = NN;
  while (lo < hi){
    int mid = (lo + hi) >> 1;
    if (batch[mid] < g) lo = mid + 1; else hi = mid;
  }
  gptr[g] = lo;
}

// ---------------- K2: sumh[n] = sum over fixed-capacity edge list of h[src] ----------------
// 4 nodes per wave (quarter-waves, uint4 = 16 B/lane): one instruction gathers 4 full
// 256B rows = 1KB payload (was 512B) -> half the issue slots; 4-deep batch = 4KB in flight.
// High-occupancy standalone kernel (round-10 lesson: never co-locate with MFMA).
__global__ __launch_bounds__(256) void aggregate_bf16(
    const uint4* __restrict__ m4, const int* __restrict__ deg,
    const int* __restrict__ csrf, uint4* __restrict__ aggr4)
{
  int t = threadIdx.x;
  int lane16 = t & 15;
  int nid = blockIdx.x*16 + (t >> 4);      // grid 3125 * 16 = 50000 exactly
  int cnt = deg[nid]; if (cnt > CAP) cnt = CAP;
  const int* lst = csrf + (nid << 6);
  float a0=0.f,a1=0.f,a2=0.f,a3=0.f,a4=0.f,a5=0.f,a6=0.f,a7=0.f;
  int j = 0;
  for (; j + 3 < cnt; j += 4){
    int i0 = lst[j], i1 = lst[j+1], i2 = lst[j+2], i3 = lst[j+3];
    uint4 v0 = m4[(size_t)i0*16 + lane16];
    uint4 v1 = m4[(size_t)i1*16 + lane16];
    uint4 v2 = m4[(size_t)i2*16 + lane16];
    uint4 v3 = m4[(size_t)i3*16 + lane16];
    a0 += __uint_as_float(v0.x << 16) + __uint_as_float(v1.x << 16)
        + __uint_as_float(v2.x << 16) + __uint_as_float(v3.x << 16);
    a1 += __uint_as_float(v0.x & 0xFFFF0000u) + __uint_as_float(v1.x & 0xFFFF0000u)
        + __uint_as_float(v2.x & 0xFFFF0000u) + __uint_as_float(v3.x & 0xFFFF0000u);
    a2 += __uint_as_float(v0.y << 16) + __uint_as_float(v1.y << 16)
        + __uint_as_float(v2.y << 16) + __uint_as_float(v3.y << 16);
    a3 += __uint_as_float(v0.y & 0xFFFF0000u) + __uint_as_float(v1.y & 0xFFFF0000u)
        + __uint_as_float(v2.y & 0xFFFF0000u) + __uint_as_float(v3.y & 0xFFFF0000u);
    a4 += __uint_as_float(v0.z << 16) + __uint_as_float(v1.z << 16)
        + __uint_as_float(v2.z << 16) + __uint_as_float(v3.z << 16);
    a5 += __uint_as_float(v0.z & 0xFFFF0000u) + __uint_as_float(v1.z & 0xFFFF0000u)
        + __uint_as_float(v2.z & 0xFFFF0000u) + __uint_as_float(v3.z & 0xFFFF0000u);
    a6 += __uint_as_float(v0.w << 16) + __uint_as_float(v1.w << 16)
        + __uint_as_float(v2.w << 16) + __uint_as_float(v3.w << 16);
    a7 += __uint_as_float(v0.w & 0xFFFF0000u) + __uint_as_float(v1.w & 0xFFFF0000u)
        + __uint_as_float(v2.w & 0xFFFF0000u) + __uint_as_float(v3.w & 0xFFFF0000u);
  }
  for (; j < cnt; j++){
    int s = lst[j];
    uint4 v = m4[(size_t)s*16 + lane16];
    a0 += __uint_as_float(v.x << 16);
    a1 += __uint_as_float(v.x & 0xFFFF0000u);
    a2 += __uint_as_float(v.y << 16);
    a3 += __uint_as_float(v.y & 0xFFFF0000u);
    a4 += __uint_as_float(v.z << 16);
    a5 += __uint_as_float(v.z & 0xFFFF0000u);
    a6 += __uint_as_float(v.w << 16);
    a7 += __uint_as_float(v.w & 0xFFFF0000u);
  }
  uint4 o;
  o.x = (uint)f2bf(a0) | ((uint)f2bf(a1) << 16);
  o.y = (uint)f2bf(a2) | ((uint)f2bf(a3) << 16);
  o.z = (uint)f2bf(a4) | ((uint)f2bf(a5) << 16);
  o.w = (uint)f2bf(a6) | ((uint)f2bf(a7) << 16);
  aggr4[(size_t)nid*16 + lane16] = o;
}

// ---------------- K3: fused GRU via MFMA; 64 nodes/block, 4x weight reuse ----------------
// (round-9 keeper: best of 5 probed GRU structures — do not re-split feats or fuse gather)
__global__ __launch_bounds__(256, 2) void gru_mfma4(
    const ushort* __restrict__ sumh_bf, ushort* __restrict__ h_bf_out,
    const ushort* __restrict__ h_bf_in,
    const ushort* __restrict__ veffT, const ushort* __restrict__ whh_bf,
    const float* __restrict__ bs)
{
  __shared__ __align__(16) ushort lds_in[16384];       // 32 KB: 32 chunks of 1 KB
  __shared__ __align__(16) ushort lds_out[64*136];     // 17 KB hv bf16, stride 136
  int t = threadIdx.x;
  int wv = t >> 6, lane = t & 63;
  int mrow = lane & 15, quad = lane >> 4;
  int nb = blockIdx.x * 64;

  #pragma unroll
  for (int q = 0; q < 8; q++){
    int c = wv*8 + q;                      // c = arr*16 + tt*4 + kc
    int arr = c >> 4, tt = (c >> 2) & 3, kc = c & 3;
    const ushort* srcb = arr ? h_bf_in : sumh_bf;
    int node = nb + tt*16 + mrow; if (node >= NN) node = NN-1;
    uint4 v = *(const uint4*)&srcb[(size_t)node*HD + kc*32 + quad*8];
    *(uint4*)&lds_in[c*512 + lane*8] = v;
  }
  __syncthreads();

  floatx4 aR[4][2] = {}, aZ[4][2] = {}, aIN[4][2] = {}, aHN[4][2] = {};

  #pragma unroll
  for (int kc = 0; kc < 4; kc++){
    int k0 = kc*32 + quad*8;
    short8 fa[4], fh[4];
    #pragma unroll
    for (int tt = 0; tt < 4; tt++){
      fa[tt] = load_frag(&lds_in[((tt<<2) | kc)*512 + lane*8]);
      fh[tt] = load_frag(&lds_in[(16 | (tt<<2) | kc)*512 + lane*8]);
    }
    #pragma unroll
    for (int ftl = 0; ftl < 2; ftl++){
      size_t wo = (size_t)((wv*2 + ftl)*16 + mrow)*HD + k0;
      short8 vir = load_frag(&veffT[wo]);
      short8 viz = load_frag(&veffT[128*HD + wo]);
      short8 vin = load_frag(&veffT[256*HD + wo]);
      short8 whr = load_frag(&whh_bf[wo]);
      short8 whz = load_frag(&whh_bf[128*HD + wo]);
      short8 whn = load_frag(&whh_bf[256*HD + wo]);
      #pragma unroll
      for (int tt = 0; tt < 4; tt++){
        aR[tt][ftl]  = MFMA(fa[tt], vir, aR[tt][ftl]);
        aR[tt][ftl]  = MFMA(fh[tt], whr, aR[tt][ftl]);
        aZ[tt][ftl]  = MFMA(fa[tt], viz, aZ[tt][ftl]);
        aZ[tt][ftl]  = MFMA(fh[tt], whz, aZ[tt][ftl]);
        aIN[tt][ftl] = MFMA(fa[tt], vin, aIN[tt][ftl]);
        aHN[tt][ftl] = MFMA(fh[tt], whn, aHN[tt][ftl]);
      }
    }
  }

  #pragma unroll
  for (int ftl = 0; ftl < 2; ftl++){
    int feat = wv*32 + ftl*16 + mrow;
    float br  = bs[feat], bz = bs[128+feat], bin = bs[256+feat], bhn = bs[384+feat];
    int kw = ftl*16 + mrow;
    int qq = kw >> 3, jj = kw & 7;
    #pragma unroll
    for (int tt = 0; tt < 4; tt++){
      int cho = (16 | (tt<<2) | wv)*512;         // h chunk, kc = wv
      #pragma unroll
      for (int r = 0; r < 4; r++){
        int nrow = quad*4 + r;
        float rr = sigmf(aR[tt][ftl][r] + br);
        float zz = sigmf(aZ[tt][ftl][r] + bz);
        float nn = tanhff(aIN[tt][ftl][r] + bin + rr*(aHN[tt][ftl][r] + bhn));
        float ho = bf2f(lds_in[cho + (qq*16 + nrow)*8 + jj]);
        float hv = (1.f - zz)*nn + zz*ho;
        lds_out[(tt*16 + nrow)*136 + feat] = f2bf(hv);
      }
    }
  }
  __syncthreads();

  #pragma unroll
  for (int p = 0; p < 4; p++){
    int chunk = p*256 + t;
    int node = chunk >> 4, f = (chunk & 15)*8;
    int ng = nb + node;
    if (ng < NN){
      uint4 v = *(const uint4*)&lds_out[node*136 + f];
      *(uint4*)&h_bf_out[(size_t)ng*HD + f] = v;
    }
  }
}

// ---------------- local head: relu(hbf @ local_w^T + b) -> fp32 ----------------
__global__ __launch_bounds__(256) void local_gemm_mfma(
    const ushort* __restrict__ hbf, const ushort* __restrict__ lw_bf,
    const float* __restrict__ bias, float* __restrict__ local)
{
  int wv = threadIdx.x >> 6, lane = threadIdx.x & 63;
  int mt = blockIdx.x*4 + wv;
  if (mt >= NN/16) return;
  int m0 = mt*16, mrow = lane & 15, quad = lane >> 4;
  floatx4 acc[8] = {};
  for (int kc = 0; kc < 4; kc++){
    int k0 = kc*32 + quad*8;
    short8 a = load_frag(&hbf[(size_t)(m0 + mrow)*HD + k0]);
    #pragma unroll
    for (int ft = 0; ft < 8; ft++){
      short8 b = load_frag(&lw_bf[(size_t)(ft*16 + mrow)*HD + k0]);
      acc[ft] = MFMA(a, b, acc[ft]);
    }
  }
  #pragma unroll
  for (int ft = 0; ft < 8; ft++){
    float bv = bias[ft*16 + mrow];
    #pragma unroll
    for (int r = 0; r < 4; r++){
      int n = m0 + quad*4 + r;
      local[(size_t)n*HD + ft*16 + mrow] = fmaxf(acc[ft][r] + bv, 0.f);
    }
  }
}

// ---------------- segmented mean-pool (batch sorted, zero atomics) ----------------
__global__ __launch_bounds__(256) void pool_kernel(
    const float* __restrict__ local, const int* __restrict__ gptr,
    float* __restrict__ pooled)
{
  __shared__ float4 red[8][32];
  int g = blockIdx.x;
  int lane = threadIdx.x & 31;
  int st = threadIdx.x >> 5;
  int s0 = gptr[g], s1 = gptr[g+1];
  float4 acc = make_float4(0,0,0,0);
  for (int n = s0 + st; n < s1; n += 8){
    float4 v = *(const float4*)&local[(size_t)n*HD + lane*4];
    acc.x += v.x; acc.y += v.y; acc.z += v.z; acc.w += v.w;
  }
  red[st][lane] = acc;
  __syncthreads();
  if (st == 0){
    float4 s = red[0][lane];
    #pragma unroll
    for (int i=1;i<8;i++){
      float4 v = red[i][lane];
      s.x += v.x; s.y += v.y; s.z += v.z; s.w += v.w;
    }
    float cnt = (float)(s1 - s0);
    if (cnt < 1.0f) cnt = 1.0f;
    float inv = 1.0f / cnt;
    s.x *= inv; s.y *= inv; s.z *= inv; s.w *= inv;
    *(float4*)&pooled[g*HD + lane*4] = s;
  }
}

// ---------------- classifier + log_softmax ----------------
__global__ __launch_bounds__(64) void classifier_kernel(
    const float* __restrict__ pooled,
    const float* __restrict__ gw, const float* __restrict__ gb,
    float* __restrict__ out)
{
  int g = blockIdx.x;
  int lane = threadIdx.x;
  float p0 = pooled[g*HD + lane];
  float p1 = pooled[g*HD + 64 + lane];
  float vals[NC];
  #pragma unroll
  for (int c=0;c<NC;c++){
    float s = p0*gw[c*HD + lane] + p1*gw[c*HD + 64 + lane];
    #pragma unroll
    for (int off=32; off>0; off>>=1) s += __shfl_down(s, off, 64);
    vals[c] = s;
  }
  if (lane == 0){
    float mx = -1e30f;
    #pragma unroll
    for (int c=0;c<NC;c++){ vals[c] += gb[c]; mx = fmaxf(mx, vals[c]); }
    float se = 0.f;
    #pragma unroll
    for (int c=0;c<NC;c++) se += __expf(vals[c] - mx);
    float lse = mx + __logf(se);
    #pragma unroll
    for (int c=0;c<NC;c++) out[g*NC + c] = vals[c] - lse;
  }
}

extern "C" void kernel_launch(void* const* d_in, const int* in_sizes, int n_in,
                              void* d_out, int out_size, void* d_ws, size_t ws_size,
                              hipStream_t stream)
{
  const float* x        = (const float*)d_in[0];
  const int*   ei       = (const int*)  d_in[1];
  const int*   batch    = (const int*)  d_in[2];
  const float* W        = (const float*)d_in[3];
  const float* w_ih     = (const float*)d_in[4];
  const float* w_hh     = (const float*)d_in[5];
  const float* b_ih     = (const float*)d_in[6];
  const float* b_hh     = (const float*)d_in[7];
  const float* local_w  = (const float*)d_in[8];
  const float* local_b  = (const float*)d_in[9];
  const float* global_w = (const float*)d_in[10];
  const float* global_b = (const float*)d_in[11];
  float* out = (float*)d_out;

  // workspace layout
  char* base = (char*)d_ws;
  int*    csr_fixed = (int*)base;                     // 12.8 MB (NN*64 ints)
  char*   R       = base + 25600000;                  // 25.6 MB multi-use region
  ushort* sumh_bf = (ushort*)R;                       //   12.8 MB (live during layers)
  ushort* veffT   = (ushort*)(R + 12800000);          //   384 KB (live during layers)
  ushort* whh_bf  = (ushort*)(R + 13193216);          //   96 KB  (live during layers)
  float*  bsums   = (float*)(R + 13291520);           //   2 KB   (live during layers)
  float*  local   = (float*)R;                        //   25.6 MB (after layers)
  ushort* xbf     = (ushort*)(base + 51200000);       // 12.8 MB
  ushort* hbf     = (ushort*)(base + 64000000);       // 12.8 MB
  ushort* lw_bf   = (ushort*)(base + 76800000);       // 32 KB
  float*  pooled  = (float*)(base + 76832768);        // 128 KB
  int* deg        = (int*)(base + 76963840);          // NN
  int* gptr       = deg + NN;                         // NG+1

  const int* esrc = ei;
  const int* edst = ei + NE;

  hipMemsetAsync(deg, 0, NN*sizeof(int), stream);
  prep_weights_bf16<<<259, 256, 0, stream>>>(w_hh, local_w, b_ih, b_hh, whh_bf, lw_bf, bsums);
  veff_kernel<<<768, 256, 0, stream>>>(W, w_ih, veffT);
  convert_x<<<6250, 256, 0, stream>>>((const float4*)x, (ushort4*)xbf);
  fill_csr_direct<<<3125, 256, 0, stream>>>(esrc, edst, deg, csr_fixed);
  graph_ptr_kernel<<<5, 64, 0, stream>>>(batch, gptr);

  // layers: high-occ quarter-wave gather, then 64-node full-feat MFMA GRU
  const ushort* hin_b = xbf;
  for (int l = 0; l < NL; l++){
    aggregate_bf16<<<3125, 256, 0, stream>>>((const uint4*)hin_b, deg, csr_fixed, (uint4*)sumh_bf);
    gru_mfma4<<<782, 256, 0, stream>>>(sumh_bf, hbf, hin_b,
                                       veffT + (size_t)l*49152, whh_bf, bsums);
    hin_b = hbf;
  }

  local_gemm_mfma<<<782, 256, 0, stream>>>(hbf, lw_bf, local_b, local);
  pool_kernel<<<NG, 256, 0, stream>>>(local, gptr, pooled);
  classifier_kernel<<<NG, 64, 0, stream>>>(pooled, global_w, global_b, out);
}